// Round 1
// baseline (452.765 us; speedup 1.0000x reference)
//
#include <hip/hip_runtime.h>
#include <cstdint>
#include <type_traits>

// ---------------- common types / helpers ----------------
typedef __attribute__((ext_vector_type(8))) short bf16x8;   // 8 bf16 in 4 VGPRs
typedef __attribute__((ext_vector_type(4))) float f32x4;

typedef unsigned int __attribute__((address_space(1))) as1_uint;
typedef unsigned int __attribute__((address_space(3))) as3_uint;

__device__ __forceinline__ void llds16(const void* g, void* l) {
  // async global->LDS, 16B per lane; LDS dst is wave-uniform base + lane*16
  __builtin_amdgcn_global_load_lds((const as1_uint*)g, (as3_uint*)l, 16, 0, 0);
}

__device__ __forceinline__ unsigned short f2bf(float f) {
  unsigned int u = __builtin_bit_cast(unsigned int, f);
  u = (u + 0x7fffu + ((u >> 16) & 1u)) >> 16;   // RNE
  return (unsigned short)u;
}
__device__ __forceinline__ float bf2f(unsigned short h) {
  unsigned int u = ((unsigned int)h) << 16;
  return __builtin_bit_cast(float, u);
}

// ---------------- elementwise convert f32 -> bf16 ----------------
__global__ __launch_bounds__(256) void cvt_f32_bf16(const float* __restrict__ in,
                                                    unsigned short* __restrict__ out, int n4) {
  int i = blockIdx.x * blockDim.x + threadIdx.x;
  int stride = gridDim.x * blockDim.x;
  for (; i < n4; i += stride) {
    float4 v = ((const float4*)in)[i];
    uint2 p;
    p.x = (unsigned)f2bf(v.x) | ((unsigned)f2bf(v.y) << 16);
    p.y = (unsigned)f2bf(v.z) | ((unsigned)f2bf(v.w) << 16);
    ((uint2*)out)[i] = p;
  }
}

// ---------------- transpose + convert: W[K][N] f32 -> Wt[N][K] bf16 ----------------
__global__ __launch_bounds__(256) void transpose_f32_bf16(const float* __restrict__ W,
                                                          unsigned short* __restrict__ Wt,
                                                          int K, int N) {
  __shared__ float tile[64][65];
  int n0 = blockIdx.x * 64, k0 = blockIdx.y * 64;
  int t = threadIdx.x;
  int lr = t >> 4, lc = (t & 15) * 4;
#pragma unroll
  for (int i = 0; i < 4; ++i) {
    int k = lr + i * 16;
    float4 v = *(const float4*)&W[(size_t)(k0 + k) * N + n0 + lc];
    tile[k][lc] = v.x; tile[k][lc + 1] = v.y; tile[k][lc + 2] = v.z; tile[k][lc + 3] = v.w;
  }
  __syncthreads();
  int n = t >> 2, kc = (t & 3) * 16;
  unsigned short* dst = &Wt[(size_t)(n0 + n) * K + k0 + kc];
#pragma unroll
  for (int j = 0; j < 16; ++j) dst[j] = f2bf(tile[kc + j][n]);
}

// ---------------- RoPE tables: cos/sin [T][32] ----------------
__global__ __launch_bounds__(256) void rope_tab(float* __restrict__ cosT, float* __restrict__ sinT) {
  int i = blockIdx.x * 256 + threadIdx.x;  // < 2048*32
  int t = i >> 5, j = i & 31;
  float inv = powf(10000.0f, -(float)j * (1.0f / 32.0f));
  float a = (float)t * inv;
  cosT[i] = cosf(a);
  sinT[i] = sinf(a);
}

// ---------------- NT GEMM: C[M][N] = A[M][K] * Bt[N][K]^T  (bf16 in, fp32 acc) ----------
// m97 structure: 128x128 tile, BK=32, 4 waves 2x2, global_load_lds 16B staging.
template <typename OutT>
__global__ __launch_bounds__(256) void gemm_nt(const unsigned short* __restrict__ A,
                                               const unsigned short* __restrict__ Bt,
                                               OutT* __restrict__ C, int M, int N, int K) {
  __shared__ unsigned short As[128 * 32];
  __shared__ unsigned short Bs[128 * 32];
  const int tid = threadIdx.x;
  const int w = tid >> 6, lane = tid & 63;
  const int l15 = lane & 15, lg = lane >> 4;
  const int wr = w >> 1, wc = w & 1;
  const int m0 = blockIdx.y * 128, n0 = blockIdx.x * 128;

  f32x4 acc[4][4] = {};
  const int nk = K >> 5;
  for (int kt = 0; kt < nk; ++kt) {
    const int k0 = kt * 32;
    __syncthreads();
#pragma unroll
    for (int i = 0; i < 2; ++i) {
      int c = w + i * 4;                       // chunk 0..7, wave-uniform
      int o = c * 1024 + lane * 16;            // byte offset in 8KB tile
      int row = o >> 6, kb = o & 63;           // 64B per row (32 bf16)
      llds16((const char*)A + ((size_t)(m0 + row) * K + k0) * 2 + kb,
             (char*)As + c * 1024);
      llds16((const char*)Bt + ((size_t)(n0 + row) * K + k0) * 2 + kb,
             (char*)Bs + c * 1024);
    }
    __syncthreads();
    bf16x8 af[4], bfr[4];
#pragma unroll
    for (int m = 0; m < 4; ++m)
      af[m] = *(const bf16x8*)&As[(wr * 64 + m * 16 + l15) * 32 + lg * 8];
#pragma unroll
    for (int n = 0; n < 4; ++n)
      bfr[n] = *(const bf16x8*)&Bs[(wc * 64 + n * 16 + l15) * 32 + lg * 8];
#pragma unroll
    for (int m = 0; m < 4; ++m)
#pragma unroll
      for (int n = 0; n < 4; ++n)
        acc[m][n] = __builtin_amdgcn_mfma_f32_16x16x32_bf16(af[m], bfr[n], acc[m][n], 0, 0, 0);
  }
#pragma unroll
  for (int m = 0; m < 4; ++m)
#pragma unroll
    for (int n = 0; n < 4; ++n) {
      int row = m0 + wr * 64 + m * 16 + lg * 4;
      int col = n0 + wc * 64 + n * 16 + l15;
#pragma unroll
      for (int r = 0; r < 4; ++r) {
        if constexpr (std::is_same<OutT, float>::value)
          C[(size_t)(row + r) * N + col] = acc[m][n][r];
        else
          C[(size_t)(row + r) * N + col] = f2bf(acc[m][n][r]);
      }
    }
}

// ---------------- per-head RMSNorm + RoPE + relayout ----------------
// qkv bf16 [B*T][3C] -> Qr/Kr/Vr bf16 [B*H][T][64]; Q pre-scaled by 1/8 (exact in bf16)
__global__ __launch_bounds__(256) void qkv_post(const unsigned short* __restrict__ qkv,
                                                const float* __restrict__ qw,
                                                const float* __restrict__ kw,
                                                const float* __restrict__ cosT,
                                                const float* __restrict__ sinT,
                                                unsigned short* __restrict__ Qr,
                                                unsigned short* __restrict__ Kr,
                                                unsigned short* __restrict__ Vr) {
  int bt = blockIdx.x;
  int b = bt >> 11, t = bt & 2047;
  int tid = threadIdx.x, h = tid >> 4, g = tid & 15, d0 = g * 4;
  const unsigned short* base = qkv + (size_t)bt * 3072;
  int dm = d0 & 31;
  float4 cv = *(const float4*)&cosT[t * 32 + dm];
  float4 sv = *(const float4*)&sinT[t * 32 + dm];
  float sgn = (g < 8) ? -1.0f : 1.0f;
  size_t oofs = (((size_t)(b * 16 + h)) * 2048 + t) * 64 + d0;

#pragma unroll
  for (int s = 0; s < 2; ++s) {
    const float* wt = s ? kw : qw;
    float scale = s ? 1.0f : 0.125f;
    unsigned short* outp = s ? Kr : Qr;
    ushort4 raw = *(const ushort4*)(base + s * 1024 + h * 64 + d0);
    float x0 = bf2f(raw.x), x1 = bf2f(raw.y), x2 = bf2f(raw.z), x3 = bf2f(raw.w);
    float ssq = x0 * x0 + x1 * x1 + x2 * x2 + x3 * x3;
    ssq += __shfl_xor(ssq, 1); ssq += __shfl_xor(ssq, 2);
    ssq += __shfl_xor(ssq, 4); ssq += __shfl_xor(ssq, 8);
    float f = rsqrtf(ssq * (1.0f / 64.0f) + 1e-5f);
    float4 w4 = *(const float4*)&wt[d0];
    float n0 = x0 * f * w4.x, n1 = x1 * f * w4.y, n2 = x2 * f * w4.z, n3 = x3 * f * w4.w;
    float p0 = __shfl_xor(n0, 8), p1 = __shfl_xor(n1, 8), p2 = __shfl_xor(n2, 8), p3 = __shfl_xor(n3, 8);
    float o0 = (n0 * cv.x + sgn * p0 * sv.x) * scale;
    float o1 = (n1 * cv.y + sgn * p1 * sv.y) * scale;
    float o2 = (n2 * cv.z + sgn * p2 * sv.z) * scale;
    float o3 = (n3 * cv.w + sgn * p3 * sv.w) * scale;
    uint2 pk;
    pk.x = (unsigned)f2bf(o0) | ((unsigned)f2bf(o1) << 16);
    pk.y = (unsigned)f2bf(o2) | ((unsigned)f2bf(o3) << 16);
    *(uint2*)(outp + oofs) = pk;
  }
  // V: straight copy (already bf16)
  ushort4 rv = *(const ushort4*)(base + 2048 + h * 64 + d0);
  *(ushort4*)(Vr + oofs) = rv;
}

// ---------------- causal flash attention ----------------
// Q,K,V: [B*H][T][64] bf16 (Q pre-scaled). Y: [B][T][H*64] bf16.
// 64 q-rows per block (4 waves x 16), KV tiles of 64.
__global__ __launch_bounds__(256) void attn_fwd(const unsigned short* __restrict__ Q,
                                                const unsigned short* __restrict__ K,
                                                const unsigned short* __restrict__ V,
                                                unsigned short* __restrict__ Y) {
  const int qt = (int)gridDim.x - 1 - (int)blockIdx.x;  // heavy blocks dispatch first
  const int bh = blockIdx.y;
  const int b = bh >> 4, h = bh & 15;
  const int tid = threadIdx.x;
  const int w = tid >> 6, lane = tid & 63;
  const int l15 = lane & 15, lg = lane >> 4;

  __shared__ unsigned short Kl[64][72];     // [k][d], +8 pad -> 144B stride
  __shared__ unsigned short Vt[64][72];     // [d][k]
  __shared__ unsigned short Pl[4][16][72];  // per-wave P [q][k]

  const int qbase = qt * 64;
  const size_t bhT = (size_t)bh * 2048;

  const unsigned short* Qp = Q + (bhT + qbase + w * 16 + l15) * 64 + lg * 8;
  bf16x8 aq[2];
  aq[0] = *(const bf16x8*)(Qp);
  aq[1] = *(const bf16x8*)(Qp + 32);

  f32x4 o[4] = {};
  float mrow[4], lrow[4];
#pragma unroll
  for (int r = 0; r < 4; ++r) { mrow[r] = -INFINITY; lrow[r] = 0.0f; }

  for (int kt = 0; kt <= qt; ++kt) {
    __syncthreads();
#pragma unroll
    for (int i = 0; i < 2; ++i) {
      int c = i * 256 + tid;            // 0..511 chunks of 8 bf16
      int row = c >> 3, dc = (c & 7) * 8;
      size_t gofs = (bhT + kt * 64 + row) * 64 + dc;
      bf16x8 kv = *(const bf16x8*)(K + gofs);
      *(bf16x8*)&Kl[row][dc] = kv;
      bf16x8 vv = *(const bf16x8*)(V + gofs);
#pragma unroll
      for (int j = 0; j < 8; ++j) Vt[dc + j][row] = (unsigned short)vv[j];
    }
    __syncthreads();

    f32x4 s[4] = {};
#pragma unroll
    for (int n = 0; n < 4; ++n)
#pragma unroll
      for (int ks = 0; ks < 2; ++ks) {
        bf16x8 bk = *(const bf16x8*)&Kl[n * 16 + l15][ks * 32 + lg * 8];
        s[n] = __builtin_amdgcn_mfma_f32_16x16x32_bf16(aq[ks], bk, s[n], 0, 0, 0);
      }

    if (kt == qt) {
#pragma unroll
      for (int n = 0; n < 4; ++n) {
        int kg = kt * 64 + n * 16 + l15;
#pragma unroll
        for (int r = 0; r < 4; ++r) {
          int qg = qbase + w * 16 + lg * 4 + r;
          if (kg > qg) s[n][r] = -1e30f;
        }
      }
    }

    float corr[4], psum[4];
#pragma unroll
    for (int r = 0; r < 4; ++r) {
      float mx = fmaxf(fmaxf(s[0][r], s[1][r]), fmaxf(s[2][r], s[3][r]));
      mx = fmaxf(mx, __shfl_xor(mx, 1));
      mx = fmaxf(mx, __shfl_xor(mx, 2));
      mx = fmaxf(mx, __shfl_xor(mx, 4));
      mx = fmaxf(mx, __shfl_xor(mx, 8));
      float nm = fmaxf(mrow[r], mx);
      corr[r] = __expf(mrow[r] - nm);   // -inf -> 0 on first tile
      mrow[r] = nm;
      psum[r] = 0.0f;
    }
#pragma unroll
    for (int n = 0; n < 4; ++n)
#pragma unroll
      for (int r = 0; r < 4; ++r) {
        float p = __expf(s[n][r] - mrow[r]);
        psum[r] += p;
        Pl[w][lg * 4 + r][n * 16 + l15] = f2bf(p);
      }
    asm volatile("" ::: "memory");  // keep P stores before P reads (HW LDS is in-order per wave)
#pragma unroll
    for (int r = 0; r < 4; ++r) {
      psum[r] += __shfl_xor(psum[r], 1);
      psum[r] += __shfl_xor(psum[r], 2);
      psum[r] += __shfl_xor(psum[r], 4);
      psum[r] += __shfl_xor(psum[r], 8);
      lrow[r] = lrow[r] * corr[r] + psum[r];
    }
#pragma unroll
    for (int df = 0; df < 4; ++df)
#pragma unroll
      for (int r = 0; r < 4; ++r) o[df][r] *= corr[r];

    bf16x8 ap[2];
    ap[0] = *(const bf16x8*)&Pl[w][l15][lg * 8];
    ap[1] = *(const bf16x8*)&Pl[w][l15][32 + lg * 8];
#pragma unroll
    for (int df = 0; df < 4; ++df)
#pragma unroll
      for (int ks = 0; ks < 2; ++ks) {
        bf16x8 bv = *(const bf16x8*)&Vt[df * 16 + l15][ks * 32 + lg * 8];
        o[df] = __builtin_amdgcn_mfma_f32_16x16x32_bf16(ap[ks], bv, o[df], 0, 0, 0);
      }
  }

#pragma unroll
  for (int r = 0; r < 4; ++r) {
    float inv = 1.0f / lrow[r];
    size_t q = qbase + w * 16 + lg * 4 + r;
    unsigned short* yp = Y + ((size_t)b * 2048 + q) * 1024 + h * 64;
#pragma unroll
    for (int df = 0; df < 4; ++df) yp[df * 16 + l15] = f2bf(o[df][r] * inv);
  }
}

// ---------------- launch ----------------
extern "C" void kernel_launch(void* const* d_in, const int* in_sizes, int n_in,
                              void* d_out, int out_size, void* d_ws, size_t ws_size,
                              hipStream_t stream) {
  const float* x = (const float*)d_in[0];
  const float* Wqkv = (const float*)d_in[1];
  const float* Wproj = (const float*)d_in[2];
  const float* qw = (const float*)d_in[3];
  const float* kw = (const float*)d_in[4];
  float* out = (float*)d_out;

  char* ws = (char*)d_ws;
  unsigned short* xb = (unsigned short*)ws;        ws += (size_t)8192 * 1024 * 2;
  unsigned short* wqkvt = (unsigned short*)ws;     ws += (size_t)3072 * 1024 * 2;
  unsigned short* wprojt = (unsigned short*)ws;    ws += (size_t)1024 * 1024 * 2;
  unsigned short* qkvb = (unsigned short*)ws;      ws += (size_t)8192 * 3072 * 2;
  unsigned short* Qr = (unsigned short*)ws;        ws += (size_t)64 * 2048 * 64 * 2;
  unsigned short* Kr = (unsigned short*)ws;        ws += (size_t)64 * 2048 * 64 * 2;
  unsigned short* Vr = (unsigned short*)ws;        ws += (size_t)64 * 2048 * 64 * 2;
  unsigned short* yb = (unsigned short*)ws;        ws += (size_t)8192 * 1024 * 2;
  float* cosT = (float*)ws;                        ws += (size_t)2048 * 32 * 4;
  float* sinT = (float*)ws;                        ws += (size_t)2048 * 32 * 4;

  cvt_f32_bf16<<<2048, 256, 0, stream>>>(x, xb, 8192 * 1024 / 4);
  transpose_f32_bf16<<<dim3(48, 16), 256, 0, stream>>>(Wqkv, wqkvt, 1024, 3072);
  transpose_f32_bf16<<<dim3(16, 16), 256, 0, stream>>>(Wproj, wprojt, 1024, 1024);
  rope_tab<<<256, 256, 0, stream>>>(cosT, sinT);
  gemm_nt<unsigned short><<<dim3(24, 64), 256, 0, stream>>>(xb, wqkvt, qkvb, 8192, 3072, 1024);
  qkv_post<<<8192, 256, 0, stream>>>(qkvb, qw, kw, cosT, sinT, Qr, Kr, Vr);
  attn_fwd<<<dim3(32, 64), 256, 0, stream>>>(Qr, Kr, Vr, yb);
  gemm_nt<float><<<dim3(8, 64), 256, 0, stream>>>(yb, wprojt, out, 8192, 1024, 1024);
}

// Round 2
// 356.442 us; speedup vs baseline: 1.2702x; 1.2702x over previous
//
#include <hip/hip_runtime.h>
#include <cstdint>
#include <type_traits>

// ---------------- common types / helpers ----------------
typedef __attribute__((ext_vector_type(8))) short bf16x8;   // 8 bf16 in 4 VGPRs
typedef __attribute__((ext_vector_type(4))) float f32x4;

typedef unsigned int __attribute__((address_space(1))) as1_uint;
typedef unsigned int __attribute__((address_space(3))) as3_uint;

__device__ __forceinline__ void llds16(const void* g, void* l) {
  // async global->LDS, 16B per lane; LDS dst is wave-uniform base + lane*16
  __builtin_amdgcn_global_load_lds((const as1_uint*)g, (as3_uint*)l, 16, 0, 0);
}

__device__ __forceinline__ unsigned short f2bf(float f) {
  unsigned int u = __builtin_bit_cast(unsigned int, f);
  u = (u + 0x7fffu + ((u >> 16) & 1u)) >> 16;   // RNE
  return (unsigned short)u;
}
__device__ __forceinline__ float bf2f(unsigned short h) {
  unsigned int u = ((unsigned int)h) << 16;
  return __builtin_bit_cast(float, u);
}

// ---------------- elementwise convert f32 -> bf16 ----------------
__global__ __launch_bounds__(256) void cvt_f32_bf16(const float* __restrict__ in,
                                                    unsigned short* __restrict__ out, int n4) {
  int i = blockIdx.x * blockDim.x + threadIdx.x;
  int stride = gridDim.x * blockDim.x;
  for (; i < n4; i += stride) {
    float4 v = ((const float4*)in)[i];
    uint2 p;
    p.x = (unsigned)f2bf(v.x) | ((unsigned)f2bf(v.y) << 16);
    p.y = (unsigned)f2bf(v.z) | ((unsigned)f2bf(v.w) << 16);
    ((uint2*)out)[i] = p;
  }
}

// ---------------- transpose + convert: W[K][N] f32 -> Wt[N][K] bf16 ----------------
__global__ __launch_bounds__(256) void transpose_f32_bf16(const float* __restrict__ W,
                                                          unsigned short* __restrict__ Wt,
                                                          int K, int N) {
  __shared__ float tile[64][65];
  int n0 = blockIdx.x * 64, k0 = blockIdx.y * 64;
  int t = threadIdx.x;
  int lr = t >> 4, lc = (t & 15) * 4;
#pragma unroll
  for (int i = 0; i < 4; ++i) {
    int k = lr + i * 16;
    float4 v = *(const float4*)&W[(size_t)(k0 + k) * N + n0 + lc];
    tile[k][lc] = v.x; tile[k][lc + 1] = v.y; tile[k][lc + 2] = v.z; tile[k][lc + 3] = v.w;
  }
  __syncthreads();
  int n = t >> 2, kc = (t & 3) * 16;
  unsigned short* dst = &Wt[(size_t)(n0 + n) * K + k0 + kc];
#pragma unroll
  for (int j = 0; j < 16; ++j) dst[j] = f2bf(tile[kc + j][n]);
}

// ---------------- RoPE tables: cos/sin [T][32] ----------------
__global__ __launch_bounds__(256) void rope_tab(float* __restrict__ cosT, float* __restrict__ sinT) {
  int i = blockIdx.x * 256 + threadIdx.x;  // < 2048*32
  int t = i >> 5, j = i & 31;
  float inv = powf(10000.0f, -(float)j * (1.0f / 32.0f));
  float a = (float)t * inv;
  cosT[i] = cosf(a);
  sinT[i] = sinf(a);
}

// ---------------- NT GEMM: C[M][N] = A[M][K] * Bt[N][K]^T  (bf16 in, fp32 acc) ----------
template <typename OutT>
__global__ __launch_bounds__(256) void gemm_nt(const unsigned short* __restrict__ A,
                                               const unsigned short* __restrict__ Bt,
                                               OutT* __restrict__ C, int M, int N, int K) {
  __shared__ unsigned short As[128 * 32];
  __shared__ unsigned short Bs[128 * 32];
  const int tid = threadIdx.x;
  const int w = tid >> 6, lane = tid & 63;
  const int l15 = lane & 15, lg = lane >> 4;
  const int wr = w >> 1, wc = w & 1;
  const int m0 = blockIdx.y * 128, n0 = blockIdx.x * 128;

  f32x4 acc[4][4] = {};
  const int nk = K >> 5;
  for (int kt = 0; kt < nk; ++kt) {
    const int k0 = kt * 32;
    __syncthreads();
#pragma unroll
    for (int i = 0; i < 2; ++i) {
      int c = w + i * 4;                       // chunk 0..7, wave-uniform
      int o = c * 1024 + lane * 16;            // byte offset in 8KB tile
      int row = o >> 6, kb = o & 63;           // 64B per row (32 bf16)
      llds16((const char*)A + ((size_t)(m0 + row) * K + k0) * 2 + kb,
             (char*)As + c * 1024);
      llds16((const char*)Bt + ((size_t)(n0 + row) * K + k0) * 2 + kb,
             (char*)Bs + c * 1024);
    }
    __syncthreads();
    bf16x8 af[4], bfr[4];
#pragma unroll
    for (int m = 0; m < 4; ++m)
      af[m] = *(const bf16x8*)&As[(wr * 64 + m * 16 + l15) * 32 + lg * 8];
#pragma unroll
    for (int n = 0; n < 4; ++n)
      bfr[n] = *(const bf16x8*)&Bs[(wc * 64 + n * 16 + l15) * 32 + lg * 8];
#pragma unroll
    for (int m = 0; m < 4; ++m)
#pragma unroll
      for (int n = 0; n < 4; ++n)
        acc[m][n] = __builtin_amdgcn_mfma_f32_16x16x32_bf16(af[m], bfr[n], acc[m][n], 0, 0, 0);
  }
#pragma unroll
  for (int m = 0; m < 4; ++m)
#pragma unroll
    for (int n = 0; n < 4; ++n) {
      int row = m0 + wr * 64 + m * 16 + lg * 4;
      int col = n0 + wc * 64 + n * 16 + l15;
#pragma unroll
      for (int r = 0; r < 4; ++r) {
        if constexpr (std::is_same<OutT, float>::value)
          C[(size_t)(row + r) * N + col] = acc[m][n][r];
        else
          C[(size_t)(row + r) * N + col] = f2bf(acc[m][n][r]);
      }
    }
}

// ---------------- per-head RMSNorm + RoPE + relayout (Q,K only) ----------------
// qkv bf16 [B*T][3C] -> Qr/Kr bf16 [B*H][T][64]; Q pre-scaled by 1/8 (exact in bf16)
__global__ __launch_bounds__(256) void qkv_post(const unsigned short* __restrict__ qkv,
                                                const float* __restrict__ qw,
                                                const float* __restrict__ kw,
                                                const float* __restrict__ cosT,
                                                const float* __restrict__ sinT,
                                                unsigned short* __restrict__ Qr,
                                                unsigned short* __restrict__ Kr) {
  int bt = blockIdx.x;
  int b = bt >> 11, t = bt & 2047;
  int tid = threadIdx.x, h = tid >> 4, g = tid & 15, d0 = g * 4;
  const unsigned short* base = qkv + (size_t)bt * 3072;
  int dm = d0 & 31;
  float4 cv = *(const float4*)&cosT[t * 32 + dm];
  float4 sv = *(const float4*)&sinT[t * 32 + dm];
  float sgn = (g < 8) ? -1.0f : 1.0f;
  size_t oofs = (((size_t)(b * 16 + h)) * 2048 + t) * 64 + d0;

#pragma unroll
  for (int s = 0; s < 2; ++s) {
    const float* wt = s ? kw : qw;
    float scale = s ? 1.0f : 0.125f;
    unsigned short* outp = s ? Kr : Qr;
    ushort4 raw = *(const ushort4*)(base + s * 1024 + h * 64 + d0);
    float x0 = bf2f(raw.x), x1 = bf2f(raw.y), x2 = bf2f(raw.z), x3 = bf2f(raw.w);
    float ssq = x0 * x0 + x1 * x1 + x2 * x2 + x3 * x3;
    ssq += __shfl_xor(ssq, 1); ssq += __shfl_xor(ssq, 2);
    ssq += __shfl_xor(ssq, 4); ssq += __shfl_xor(ssq, 8);
    float f = rsqrtf(ssq * (1.0f / 64.0f) + 1e-5f);
    float4 w4 = *(const float4*)&wt[d0];
    float n0 = x0 * f * w4.x, n1 = x1 * f * w4.y, n2 = x2 * f * w4.z, n3 = x3 * f * w4.w;
    float p0 = __shfl_xor(n0, 8), p1 = __shfl_xor(n1, 8), p2 = __shfl_xor(n2, 8), p3 = __shfl_xor(n3, 8);
    float o0 = (n0 * cv.x + sgn * p0 * sv.x) * scale;
    float o1 = (n1 * cv.y + sgn * p1 * sv.y) * scale;
    float o2 = (n2 * cv.z + sgn * p2 * sv.z) * scale;
    float o3 = (n3 * cv.w + sgn * p3 * sv.w) * scale;
    uint2 pk;
    pk.x = (unsigned)f2bf(o0) | ((unsigned)f2bf(o1) << 16);
    pk.y = (unsigned)f2bf(o2) | ((unsigned)f2bf(o3) << 16);
    *(uint2*)(outp + oofs) = pk;
  }
}

// ---------------- V transpose: qkv V-part [B*T][...] -> Vtg [B*H][64 d][2048 t] -------
__global__ __launch_bounds__(256) void vtrans(const unsigned short* __restrict__ qkv,
                                              unsigned short* __restrict__ Vtg) {
  __shared__ unsigned short tile[64][72];
  int bh = blockIdx.y, b = bh >> 4, h = bh & 15;
  int t0 = blockIdx.x * 64;
  int tid = threadIdx.x;
  int r = tid >> 2, c0 = (tid & 3) * 16;
  const unsigned short* src = qkv + (size_t)(b * 2048 + t0 + r) * 3072 + 2048 + h * 64 + c0;
  *(bf16x8*)&tile[r][c0] = *(const bf16x8*)src;
  *(bf16x8*)&tile[r][c0 + 8] = *(const bf16x8*)(src + 8);
  __syncthreads();
  int d = tid >> 2, t4 = (tid & 3) * 16;
  unsigned short* dst = &Vtg[((size_t)bh * 64 + d) * 2048 + t0 + t4];
  unsigned short pack[16];
#pragma unroll
  for (int j = 0; j < 16; ++j) pack[j] = tile[t4 + j][d];
  *(bf16x8*)dst = *(bf16x8*)&pack[0];
  *(bf16x8*)(dst + 8) = *(bf16x8*)&pack[8];
}

// ---------------- causal flash attention ----------------
// Q,K: [B*H][T][64] bf16 (Q pre-scaled). Vtg: [B*H][64][T] bf16. Y: [B][T][H*64] bf16.
// 64 q-rows per block (4 waves x 16), KV tiles of 64. K/Vt double-buffered in
// XOR-swizzled LDS (byte ^= (row&7)<<4), staged via global_load_lds with
// pre-swizzled global source (both-sides-or-neither rule).
__global__ __launch_bounds__(256) void attn_fwd(const unsigned short* __restrict__ Q,
                                                const unsigned short* __restrict__ K,
                                                const unsigned short* __restrict__ Vtg,
                                                unsigned short* __restrict__ Y) {
  const int qt = (int)gridDim.x - 1 - (int)blockIdx.x;  // heavy blocks dispatch first
  const int bh = blockIdx.y;
  const int b = bh >> 4, h = bh & 15;
  const int tid = threadIdx.x;
  const int w = tid >> 6, lane = tid & 63;
  const int l15 = lane & 15, lg = lane >> 4;

  __shared__ unsigned short Kl[2][64 * 64];   // swizzled [k][d], 128B rows
  __shared__ unsigned short Vt[2][64 * 64];   // swizzled [d][k], 128B rows
  __shared__ unsigned short Pl[4][16][72];    // per-wave P [q][k]

  const int qbase = qt * 64;
  const size_t bhT = (size_t)bh * 2048;
  const char* Kg = (const char*)(K + bhT * 64);          // row stride 128B
  const char* Vg = (const char*)(Vtg + bhT * 64);        // row stride 4096B

  // stage K tile + Vt tile for kv-tile `kt` into buffer `buf`
  auto stage = [&](int buf, int kt) {
#pragma unroll
    for (int i = 0; i < 2; ++i) {
      int c = w * 2 + i;                     // chunk 0..7, wave-uniform
      int pos = c * 1024 + lane * 16;        // linear byte in 8KB tile
      int row = pos >> 7, cb = pos & 127;
      int srcb = cb ^ ((row & 7) << 4);      // inverse-swizzled source
      llds16(Kg + ((size_t)(kt * 64 + row)) * 128 + srcb,
             (char*)&Kl[buf][0] + c * 1024);
      llds16(Vg + (size_t)row * 4096 + (size_t)kt * 128 + srcb,
             (char*)&Vt[buf][0] + c * 1024);
    }
  };

  const unsigned short* Qp = Q + (bhT + qbase + w * 16 + l15) * 64 + lg * 8;
  bf16x8 aq[2];
  aq[0] = *(const bf16x8*)(Qp);
  aq[1] = *(const bf16x8*)(Qp + 32);

  f32x4 o[4] = {};
  float mrow[4], lrow[4];
#pragma unroll
  for (int r = 0; r < 4; ++r) { mrow[r] = -INFINITY; lrow[r] = 0.0f; }

  stage(0, 0);
  __syncthreads();

  for (int kt = 0; kt <= qt; ++kt) {
    const int cur = kt & 1;
    if (kt < qt) stage(cur ^ 1, kt + 1);
    const char* Kc = (const char*)&Kl[cur][0];
    const char* Vc = (const char*)&Vt[cur][0];

    f32x4 s[4] = {};
#pragma unroll
    for (int n = 0; n < 4; ++n) {
      int r = n * 16 + l15, sw = (r & 7) << 4;
#pragma unroll
      for (int ks = 0; ks < 2; ++ks) {
        bf16x8 bk = *(const bf16x8*)(Kc + r * 128 + ((ks * 64 + lg * 16) ^ sw));
        s[n] = __builtin_amdgcn_mfma_f32_16x16x32_bf16(aq[ks], bk, s[n], 0, 0, 0);
      }
    }

    if (kt == qt) {
#pragma unroll
      for (int n = 0; n < 4; ++n) {
        int kg = kt * 64 + n * 16 + l15;
#pragma unroll
        for (int r = 0; r < 4; ++r) {
          int qg = qbase + w * 16 + lg * 4 + r;
          if (kg > qg) s[n][r] = -1e30f;
        }
      }
    }

    float corr[4], psum[4];
#pragma unroll
    for (int r = 0; r < 4; ++r) {
      float mx = fmaxf(fmaxf(s[0][r], s[1][r]), fmaxf(s[2][r], s[3][r]));
      mx = fmaxf(mx, __shfl_xor(mx, 1));
      mx = fmaxf(mx, __shfl_xor(mx, 2));
      mx = fmaxf(mx, __shfl_xor(mx, 4));
      mx = fmaxf(mx, __shfl_xor(mx, 8));
      float nm = fmaxf(mrow[r], mx);
      corr[r] = __expf(mrow[r] - nm);   // -inf -> 0 on first tile
      mrow[r] = nm;
      psum[r] = 0.0f;
    }
#pragma unroll
    for (int n = 0; n < 4; ++n)
#pragma unroll
      for (int r = 0; r < 4; ++r) {
        float p = __expf(s[n][r] - mrow[r]);
        psum[r] += p;
        Pl[w][lg * 4 + r][n * 16 + l15] = f2bf(p);
      }
    asm volatile("" ::: "memory");  // keep P stores before P reads (per-wave LDS is in-order)
#pragma unroll
    for (int r = 0; r < 4; ++r) {
      psum[r] += __shfl_xor(psum[r], 1);
      psum[r] += __shfl_xor(psum[r], 2);
      psum[r] += __shfl_xor(psum[r], 4);
      psum[r] += __shfl_xor(psum[r], 8);
      lrow[r] = lrow[r] * corr[r] + psum[r];
    }
#pragma unroll
    for (int df = 0; df < 4; ++df)
#pragma unroll
      for (int r = 0; r < 4; ++r) o[df][r] *= corr[r];

    bf16x8 ap[2];
    ap[0] = *(const bf16x8*)&Pl[w][l15][lg * 8];
    ap[1] = *(const bf16x8*)&Pl[w][l15][32 + lg * 8];
#pragma unroll
    for (int df = 0; df < 4; ++df) {
      int r = df * 16 + l15, sw = (r & 7) << 4;
#pragma unroll
      for (int ks = 0; ks < 2; ++ks) {
        bf16x8 bv = *(const bf16x8*)(Vc + r * 128 + ((ks * 64 + lg * 16) ^ sw));
        o[df] = __builtin_amdgcn_mfma_f32_16x16x32_bf16(ap[ks], bv, o[df], 0, 0, 0);
      }
    }
    __syncthreads();  // drains next-tile staging loads; protects cur from overwrite
  }

#pragma unroll
  for (int r = 0; r < 4; ++r) {
    float inv = 1.0f / lrow[r];
    size_t q = qbase + w * 16 + lg * 4 + r;
    unsigned short* yp = Y + ((size_t)b * 2048 + q) * 1024 + h * 64;
#pragma unroll
    for (int df = 0; df < 4; ++df) yp[df * 16 + l15] = f2bf(o[df][r] * inv);
  }
}

// ---------------- launch ----------------
extern "C" void kernel_launch(void* const* d_in, const int* in_sizes, int n_in,
                              void* d_out, int out_size, void* d_ws, size_t ws_size,
                              hipStream_t stream) {
  const float* x = (const float*)d_in[0];
  const float* Wqkv = (const float*)d_in[1];
  const float* Wproj = (const float*)d_in[2];
  const float* qw = (const float*)d_in[3];
  const float* kw = (const float*)d_in[4];
  float* out = (float*)d_out;

  char* ws = (char*)d_ws;
  unsigned short* xb = (unsigned short*)ws;        ws += (size_t)8192 * 1024 * 2;
  unsigned short* wqkvt = (unsigned short*)ws;     ws += (size_t)3072 * 1024 * 2;
  unsigned short* wprojt = (unsigned short*)ws;    ws += (size_t)1024 * 1024 * 2;
  unsigned short* qkvb = (unsigned short*)ws;      ws += (size_t)8192 * 3072 * 2;
  unsigned short* Qr = (unsigned short*)ws;        ws += (size_t)64 * 2048 * 64 * 2;
  unsigned short* Kr = (unsigned short*)ws;        ws += (size_t)64 * 2048 * 64 * 2;
  unsigned short* Vtg = (unsigned short*)ws;       ws += (size_t)64 * 64 * 2048 * 2;
  unsigned short* yb = (unsigned short*)ws;        ws += (size_t)8192 * 1024 * 2;
  float* cosT = (float*)ws;                        ws += (size_t)2048 * 32 * 4;
  float* sinT = (float*)ws;                        ws += (size_t)2048 * 32 * 4;

  cvt_f32_bf16<<<2048, 256, 0, stream>>>(x, xb, 8192 * 1024 / 4);
  transpose_f32_bf16<<<dim3(48, 16), 256, 0, stream>>>(Wqkv, wqkvt, 1024, 3072);
  transpose_f32_bf16<<<dim3(16, 16), 256, 0, stream>>>(Wproj, wprojt, 1024, 1024);
  rope_tab<<<256, 256, 0, stream>>>(cosT, sinT);
  gemm_nt<unsigned short><<<dim3(24, 64), 256, 0, stream>>>(xb, wqkvt, qkvb, 8192, 3072, 1024);
  qkv_post<<<8192, 256, 0, stream>>>(qkvb, qw, kw, cosT, sinT, Qr, Kr);
  vtrans<<<dim3(32, 64), 256, 0, stream>>>(qkvb, Vtg);
  attn_fwd<<<dim3(32, 64), 256, 0, stream>>>(Qr, Kr, Vtg, yb);
  gemm_nt<float><<<dim3(8, 64), 256, 0, stream>>>(yb, wprojt, out, 8192, 1024, 1024);
}

// Round 3
// 284.871 us; speedup vs baseline: 1.5894x; 1.2512x over previous
//
#include <hip/hip_runtime.h>
#include <cstdint>
#include <type_traits>

// ---------------- common types / helpers ----------------
typedef __attribute__((ext_vector_type(8))) short bf16x8;   // 8 bf16 in 4 VGPRs
typedef __attribute__((ext_vector_type(4))) float f32x4;

typedef unsigned int __attribute__((address_space(1))) as1_uint;
typedef unsigned int __attribute__((address_space(3))) as3_uint;

__device__ __forceinline__ void llds16(const void* g, void* l) {
  // async global->LDS, 16B per lane; LDS dst is wave-uniform base + lane*16
  __builtin_amdgcn_global_load_lds((const as1_uint*)g, (as3_uint*)l, 16, 0, 0);
}

__device__ __forceinline__ unsigned short f2bf(float f) {
  unsigned int u = __builtin_bit_cast(unsigned int, f);
  u = (u + 0x7fffu + ((u >> 16) & 1u)) >> 16;   // RNE
  return (unsigned short)u;
}
__device__ __forceinline__ float bf2f(unsigned short h) {
  unsigned int u = ((unsigned int)h) << 16;
  return __builtin_bit_cast(float, u);
}

// ---------------- elementwise convert f32 -> bf16 ----------------
__global__ __launch_bounds__(256) void cvt_f32_bf16(const float* __restrict__ in,
                                                    unsigned short* __restrict__ out, int n4) {
  int i = blockIdx.x * blockDim.x + threadIdx.x;
  int stride = gridDim.x * blockDim.x;
  for (; i < n4; i += stride) {
    float4 v = ((const float4*)in)[i];
    uint2 p;
    p.x = (unsigned)f2bf(v.x) | ((unsigned)f2bf(v.y) << 16);
    p.y = (unsigned)f2bf(v.z) | ((unsigned)f2bf(v.w) << 16);
    ((uint2*)out)[i] = p;
  }
}

// ---------------- transpose + convert: W[K][N] f32 -> Wt[N][K] bf16 ----------------
__global__ __launch_bounds__(256) void transpose_f32_bf16(const float* __restrict__ W,
                                                          unsigned short* __restrict__ Wt,
                                                          int K, int N) {
  __shared__ float tile[64][65];
  int n0 = blockIdx.x * 64, k0 = blockIdx.y * 64;
  int t = threadIdx.x;
  int lr = t >> 4, lc = (t & 15) * 4;
#pragma unroll
  for (int i = 0; i < 4; ++i) {
    int k = lr + i * 16;
    float4 v = *(const float4*)&W[(size_t)(k0 + k) * N + n0 + lc];
    tile[k][lc] = v.x; tile[k][lc + 1] = v.y; tile[k][lc + 2] = v.z; tile[k][lc + 3] = v.w;
  }
  __syncthreads();
  int n = t >> 2, kc = (t & 3) * 16;
  unsigned short* dst = &Wt[(size_t)(n0 + n) * K + k0 + kc];
#pragma unroll
  for (int j = 0; j < 16; ++j) dst[j] = f2bf(tile[kc + j][n]);
}

// ---------------- RoPE tables: cos/sin [T][32] ----------------
__global__ __launch_bounds__(256) void rope_tab(float* __restrict__ cosT, float* __restrict__ sinT) {
  int i = blockIdx.x * 256 + threadIdx.x;  // < 2048*32
  int t = i >> 5, j = i & 31;
  float inv = powf(10000.0f, -(float)j * (1.0f / 32.0f));
  float a = (float)t * inv;
  cosT[i] = cosf(a);
  sinT[i] = sinf(a);
}

// ---------------- NT GEMM: C[M][N] = A[M][K] * Bt[N][K]^T  (bf16 in, fp32 acc) ----------
template <typename OutT>
__global__ __launch_bounds__(256) void gemm_nt(const unsigned short* __restrict__ A,
                                               const unsigned short* __restrict__ Bt,
                                               OutT* __restrict__ C, int M, int N, int K) {
  __shared__ unsigned short As[128 * 32];
  __shared__ unsigned short Bs[128 * 32];
  const int tid = threadIdx.x;
  const int w = tid >> 6, lane = tid & 63;
  const int l15 = lane & 15, lg = lane >> 4;
  const int wr = w >> 1, wc = w & 1;
  const int m0 = blockIdx.y * 128, n0 = blockIdx.x * 128;

  f32x4 acc[4][4] = {};
  const int nk = K >> 5;
  for (int kt = 0; kt < nk; ++kt) {
    const int k0 = kt * 32;
    __syncthreads();
#pragma unroll
    for (int i = 0; i < 2; ++i) {
      int c = w + i * 4;                       // chunk 0..7, wave-uniform
      int o = c * 1024 + lane * 16;            // byte offset in 8KB tile
      int row = o >> 6, kb = o & 63;           // 64B per row (32 bf16)
      llds16((const char*)A + ((size_t)(m0 + row) * K + k0) * 2 + kb,
             (char*)As + c * 1024);
      llds16((const char*)Bt + ((size_t)(n0 + row) * K + k0) * 2 + kb,
             (char*)Bs + c * 1024);
    }
    __syncthreads();
    bf16x8 af[4], bfr[4];
#pragma unroll
    for (int m = 0; m < 4; ++m)
      af[m] = *(const bf16x8*)&As[(wr * 64 + m * 16 + l15) * 32 + lg * 8];
#pragma unroll
    for (int n = 0; n < 4; ++n)
      bfr[n] = *(const bf16x8*)&Bs[(wc * 64 + n * 16 + l15) * 32 + lg * 8];
#pragma unroll
    for (int m = 0; m < 4; ++m)
#pragma unroll
      for (int n = 0; n < 4; ++n)
        acc[m][n] = __builtin_amdgcn_mfma_f32_16x16x32_bf16(af[m], bfr[n], acc[m][n], 0, 0, 0);
  }
#pragma unroll
  for (int m = 0; m < 4; ++m)
#pragma unroll
    for (int n = 0; n < 4; ++n) {
      int row = m0 + wr * 64 + m * 16 + lg * 4;
      int col = n0 + wc * 64 + n * 16 + l15;
#pragma unroll
      for (int r = 0; r < 4; ++r) {
        if constexpr (std::is_same<OutT, float>::value)
          C[(size_t)(row + r) * N + col] = acc[m][n][r];
        else
          C[(size_t)(row + r) * N + col] = f2bf(acc[m][n][r]);
      }
    }
}

// ---------------- per-head RMSNorm + RoPE + relayout (Q,K only) ----------------
// qkv bf16 [B*T][3C] -> Qr/Kr bf16 [B*H][T][64]
// Q pre-scaled by log2(e)/8 so attention softmax is a bare exp2.
__global__ __launch_bounds__(256) void qkv_post(const unsigned short* __restrict__ qkv,
                                                const float* __restrict__ qw,
                                                const float* __restrict__ kw,
                                                const float* __restrict__ cosT,
                                                const float* __restrict__ sinT,
                                                unsigned short* __restrict__ Qr,
                                                unsigned short* __restrict__ Kr) {
  int bt = blockIdx.x;
  int b = bt >> 11, t = bt & 2047;
  int tid = threadIdx.x, h = tid >> 4, g = tid & 15, d0 = g * 4;
  const unsigned short* base = qkv + (size_t)bt * 3072;
  int dm = d0 & 31;
  float4 cv = *(const float4*)&cosT[t * 32 + dm];
  float4 sv = *(const float4*)&sinT[t * 32 + dm];
  float sgn = (g < 8) ? -1.0f : 1.0f;
  size_t oofs = (((size_t)(b * 16 + h)) * 2048 + t) * 64 + d0;

#pragma unroll
  for (int s = 0; s < 2; ++s) {
    const float* wt = s ? kw : qw;
    float scale = s ? 1.0f : 0.18033688011112042f;   // log2(e)/8
    unsigned short* outp = s ? Kr : Qr;
    ushort4 raw = *(const ushort4*)(base + s * 1024 + h * 64 + d0);
    float x0 = bf2f(raw.x), x1 = bf2f(raw.y), x2 = bf2f(raw.z), x3 = bf2f(raw.w);
    float ssq = x0 * x0 + x1 * x1 + x2 * x2 + x3 * x3;
    ssq += __shfl_xor(ssq, 1); ssq += __shfl_xor(ssq, 2);
    ssq += __shfl_xor(ssq, 4); ssq += __shfl_xor(ssq, 8);
    float f = rsqrtf(ssq * (1.0f / 64.0f) + 1e-5f);
    float4 w4 = *(const float4*)&wt[d0];
    float n0 = x0 * f * w4.x, n1 = x1 * f * w4.y, n2 = x2 * f * w4.z, n3 = x3 * f * w4.w;
    float p0 = __shfl_xor(n0, 8), p1 = __shfl_xor(n1, 8), p2 = __shfl_xor(n2, 8), p3 = __shfl_xor(n3, 8);
    float o0 = (n0 * cv.x + sgn * p0 * sv.x) * scale;
    float o1 = (n1 * cv.y + sgn * p1 * sv.y) * scale;
    float o2 = (n2 * cv.z + sgn * p2 * sv.z) * scale;
    float o3 = (n3 * cv.w + sgn * p3 * sv.w) * scale;
    uint2 pk;
    pk.x = (unsigned)f2bf(o0) | ((unsigned)f2bf(o1) << 16);
    pk.y = (unsigned)f2bf(o2) | ((unsigned)f2bf(o3) << 16);
    *(uint2*)(outp + oofs) = pk;
  }
}

// ---------------- V transpose: qkv V-part [B*T][...] -> Vtg [B*H][64 d][2048 t] -------
__global__ __launch_bounds__(256) void vtrans(const unsigned short* __restrict__ qkv,
                                              unsigned short* __restrict__ Vtg) {
  __shared__ unsigned short tile[64][72];
  int bh = blockIdx.y, b = bh >> 4, h = bh & 15;
  int t0 = blockIdx.x * 64;
  int tid = threadIdx.x;
  int r = tid >> 2, c0 = (tid & 3) * 16;
  const unsigned short* src = qkv + (size_t)(b * 2048 + t0 + r) * 3072 + 2048 + h * 64 + c0;
  *(bf16x8*)&tile[r][c0] = *(const bf16x8*)src;
  *(bf16x8*)&tile[r][c0 + 8] = *(const bf16x8*)(src + 8);
  __syncthreads();
  int d = tid >> 2, t4 = (tid & 3) * 16;
  unsigned short* dst = &Vtg[((size_t)bh * 64 + d) * 2048 + t0 + t4];
  unsigned short pack[16];
#pragma unroll
  for (int j = 0; j < 16; ++j) pack[j] = tile[t4 + j][d];
  *(bf16x8*)dst = *(bf16x8*)&pack[0];
  *(bf16x8*)(dst + 8) = *(bf16x8*)&pack[8];
}

// ---------------- causal flash attention, fixed-max softmax ----------------
// Q,K: [B*H][T][64] bf16 (Q pre-scaled by log2e/8). Vtg: [B*H][64][T] bf16.
// Y: [B][T][H*64] bf16.
// 128 q-rows per block (4 waves x 32 rows = 2 m-tiles each), KV tiles of 64.
// |q.k|/8 <= 8 guaranteed (RMSNormed rows, norm 8, RoPE is a rotation), so no
// online max: p = exp2(s'), psum accumulates in-register, one reduce at end,
// no O-rescale. K/Vt double-buffered in XOR-swizzled LDS via global_load_lds.
__global__ __launch_bounds__(256) void attn_fwd(const unsigned short* __restrict__ Q,
                                                const unsigned short* __restrict__ K,
                                                const unsigned short* __restrict__ Vtg,
                                                unsigned short* __restrict__ Y) {
  const int qtb = (int)gridDim.x - 1 - (int)blockIdx.x;  // heavy blocks dispatch first
  const int bh = blockIdx.y;
  const int b = bh >> 4, h = bh & 15;
  const int tid = threadIdx.x;
  const int w = tid >> 6, lane = tid & 63;
  const int l15 = lane & 15, lg = lane >> 4;

  __shared__ unsigned short Kl[2][64 * 64];   // swizzled [k][d], 128B rows
  __shared__ unsigned short Vt[2][64 * 64];   // swizzled [d][k], 128B rows
  __shared__ unsigned short Pl[4][32][72];    // per-wave P [q_local][k]

  const int qbase = qtb * 128;
  const size_t bhT = (size_t)bh * 2048;
  const char* Kg = (const char*)(K + bhT * 64);          // row stride 128B
  const char* Vg = (const char*)(Vtg + bhT * 64);        // row stride 4096B

  auto stage = [&](int buf, int kt) {
#pragma unroll
    for (int i = 0; i < 2; ++i) {
      int c = w * 2 + i;                     // chunk 0..7, wave-uniform
      int pos = c * 1024 + lane * 16;        // linear byte in 8KB tile
      int row = pos >> 7, cb = pos & 127;
      int srcb = cb ^ ((row & 7) << 4);      // inverse-swizzled source
      llds16(Kg + ((size_t)(kt * 64 + row)) * 128 + srcb,
             (char*)&Kl[buf][0] + c * 1024);
      llds16(Vg + (size_t)row * 4096 + (size_t)kt * 128 + srcb,
             (char*)&Vt[buf][0] + c * 1024);
    }
  };

  bf16x8 aq[2][2];
#pragma unroll
  for (int mi = 0; mi < 2; ++mi) {
    const unsigned short* Qp = Q + (bhT + qbase + w * 32 + mi * 16 + l15) * 64 + lg * 8;
    aq[mi][0] = *(const bf16x8*)(Qp);
    aq[mi][1] = *(const bf16x8*)(Qp + 32);
  }

  f32x4 o[2][4] = {};
  float psum[2][4] = {};

  stage(0, 0);
  __syncthreads();

  const int ktmax = 2 * qtb + 1;
  for (int kt = 0; kt <= ktmax; ++kt) {
    const int cur = kt & 1;
    if (kt < ktmax) stage(cur ^ 1, kt + 1);

    // skip waves whose 32 rows are entirely above this kv tile (fully masked)
    if (kt * 64 <= qbase + w * 32 + 31) {
      const char* Kc = (const char*)&Kl[cur][0];
      const char* Vc = (const char*)&Vt[cur][0];

      f32x4 s[2][4] = {};
#pragma unroll
      for (int n = 0; n < 4; ++n) {
        int r = n * 16 + l15, sw = (r & 7) << 4;
#pragma unroll
        for (int ks = 0; ks < 2; ++ks) {
          bf16x8 bk = *(const bf16x8*)(Kc + r * 128 + ((ks * 64 + lg * 16) ^ sw));
#pragma unroll
          for (int mi = 0; mi < 2; ++mi)
            s[mi][n] = __builtin_amdgcn_mfma_f32_16x16x32_bf16(aq[mi][ks], bk, s[mi][n], 0, 0, 0);
        }
      }

      if (kt >= 2 * qtb) {   // diagonal band: apply causal mask
#pragma unroll
        for (int n = 0; n < 4; ++n) {
          int kg = kt * 64 + n * 16 + l15;
#pragma unroll
          for (int mi = 0; mi < 2; ++mi)
#pragma unroll
            for (int r = 0; r < 4; ++r) {
              int qg = qbase + w * 32 + mi * 16 + lg * 4 + r;
              if (kg > qg) s[mi][n][r] = -1e30f;
            }
        }
      }

      // p = exp2(s'); accumulate per-lane psum; store P (round-half-up bf16)
#pragma unroll
      for (int mi = 0; mi < 2; ++mi)
#pragma unroll
        for (int n = 0; n < 4; ++n)
#pragma unroll
          for (int r = 0; r < 4; ++r) {
            float p = __builtin_exp2f(s[mi][n][r]);
            psum[mi][r] += p;
            unsigned int u = (__builtin_bit_cast(unsigned int, p) + 0x8000u) >> 16;
            Pl[w][mi * 16 + lg * 4 + r][n * 16 + l15] = (unsigned short)u;
          }
      asm volatile("" ::: "memory");  // keep P stores before P reads (per-wave LDS in-order)

      bf16x8 ap[2][2];
#pragma unroll
      for (int mi = 0; mi < 2; ++mi)
#pragma unroll
        for (int ks = 0; ks < 2; ++ks)
          ap[mi][ks] = *(const bf16x8*)&Pl[w][mi * 16 + l15][ks * 32 + lg * 8];

#pragma unroll
      for (int df = 0; df < 4; ++df) {
        int rr = df * 16 + l15, sw = (rr & 7) << 4;
#pragma unroll
        for (int ks = 0; ks < 2; ++ks) {
          bf16x8 bv = *(const bf16x8*)(Vc + rr * 128 + ((ks * 64 + lg * 16) ^ sw));
#pragma unroll
          for (int mi = 0; mi < 2; ++mi)
            o[mi][df] = __builtin_amdgcn_mfma_f32_16x16x32_bf16(ap[mi][ks], bv, o[mi][df], 0, 0, 0);
        }
      }
    }
    __syncthreads();  // drains next-tile staging; protects cur from overwrite
  }

#pragma unroll
  for (int mi = 0; mi < 2; ++mi)
#pragma unroll
    for (int r = 0; r < 4; ++r) {
      float l = psum[mi][r];
      l += __shfl_xor(l, 1); l += __shfl_xor(l, 2);
      l += __shfl_xor(l, 4); l += __shfl_xor(l, 8);
      float inv = 1.0f / l;
      size_t q = qbase + w * 32 + mi * 16 + lg * 4 + r;
      unsigned short* yp = Y + ((size_t)b * 2048 + q) * 1024 + h * 64;
#pragma unroll
      for (int df = 0; df < 4; ++df) yp[df * 16 + l15] = f2bf(o[mi][df][r] * inv);
    }
}

// ---------------- launch ----------------
extern "C" void kernel_launch(void* const* d_in, const int* in_sizes, int n_in,
                              void* d_out, int out_size, void* d_ws, size_t ws_size,
                              hipStream_t stream) {
  const float* x = (const float*)d_in[0];
  const float* Wqkv = (const float*)d_in[1];
  const float* Wproj = (const float*)d_in[2];
  const float* qw = (const float*)d_in[3];
  const float* kw = (const float*)d_in[4];
  float* out = (float*)d_out;

  char* ws = (char*)d_ws;
  unsigned short* xb = (unsigned short*)ws;        ws += (size_t)8192 * 1024 * 2;
  unsigned short* wqkvt = (unsigned short*)ws;     ws += (size_t)3072 * 1024 * 2;
  unsigned short* wprojt = (unsigned short*)ws;    ws += (size_t)1024 * 1024 * 2;
  unsigned short* qkvb = (unsigned short*)ws;      ws += (size_t)8192 * 3072 * 2;
  unsigned short* Qr = (unsigned short*)ws;        ws += (size_t)64 * 2048 * 64 * 2;
  unsigned short* Kr = (unsigned short*)ws;        ws += (size_t)64 * 2048 * 64 * 2;
  unsigned short* Vtg = (unsigned short*)ws;       ws += (size_t)64 * 64 * 2048 * 2;
  unsigned short* yb = (unsigned short*)ws;        ws += (size_t)8192 * 1024 * 2;
  float* cosT = (float*)ws;                        ws += (size_t)2048 * 32 * 4;
  float* sinT = (float*)ws;                        ws += (size_t)2048 * 32 * 4;

  cvt_f32_bf16<<<2048, 256, 0, stream>>>(x, xb, 8192 * 1024 / 4);
  transpose_f32_bf16<<<dim3(48, 16), 256, 0, stream>>>(Wqkv, wqkvt, 1024, 3072);
  transpose_f32_bf16<<<dim3(16, 16), 256, 0, stream>>>(Wproj, wprojt, 1024, 1024);
  rope_tab<<<256, 256, 0, stream>>>(cosT, sinT);
  gemm_nt<unsigned short><<<dim3(24, 64), 256, 0, stream>>>(xb, wqkvt, qkvb, 8192, 3072, 1024);
  qkv_post<<<8192, 256, 0, stream>>>(qkvb, qw, kw, cosT, sinT, Qr, Kr);
  vtrans<<<dim3(32, 64), 256, 0, stream>>>(qkvb, Vtg);
  attn_fwd<<<dim3(16, 64), 256, 0, stream>>>(Qr, Kr, Vtg, yb);
  gemm_nt<float><<<dim3(8, 64), 256, 0, stream>>>(yb, wprojt, out, 8192, 1024, 1024);
}

// Round 4
// 240.541 us; speedup vs baseline: 1.8823x; 1.1843x over previous
//
#include <hip/hip_runtime.h>
#include <cstdint>
#include <type_traits>

// ---------------- common types / helpers ----------------
typedef __attribute__((ext_vector_type(8))) short bf16x8;   // 8 bf16 in 4 VGPRs
typedef __attribute__((ext_vector_type(4))) float f32x4;

typedef unsigned int __attribute__((address_space(1))) as1_uint;
typedef unsigned int __attribute__((address_space(3))) as3_uint;

__device__ __forceinline__ void llds16(const void* g, void* l) {
  // async global->LDS, 16B per lane; LDS dst is wave-uniform base + lane*16
  __builtin_amdgcn_global_load_lds((const as1_uint*)g, (as3_uint*)l, 16, 0, 0);
}

__device__ __forceinline__ unsigned short f2bf(float f) {
  unsigned int u = __builtin_bit_cast(unsigned int, f);
  u = (u + 0x7fffu + ((u >> 16) & 1u)) >> 16;   // RNE
  return (unsigned short)u;
}
__device__ __forceinline__ float bf2f(unsigned short h) {
  unsigned int u = ((unsigned int)h) << 16;
  return __builtin_bit_cast(float, u);
}

// ---------------- elementwise convert f32 -> bf16 ----------------
__global__ __launch_bounds__(256) void cvt_f32_bf16(const float* __restrict__ in,
                                                    unsigned short* __restrict__ out, int n4) {
  int i = blockIdx.x * blockDim.x + threadIdx.x;
  int stride = gridDim.x * blockDim.x;
  for (; i < n4; i += stride) {
    float4 v = ((const float4*)in)[i];
    uint2 p;
    p.x = (unsigned)f2bf(v.x) | ((unsigned)f2bf(v.y) << 16);
    p.y = (unsigned)f2bf(v.z) | ((unsigned)f2bf(v.w) << 16);
    ((uint2*)out)[i] = p;
  }
}

// ---------------- transpose + convert: W[K][N] f32 -> Wt[N][K] bf16 ----------------
__global__ __launch_bounds__(256) void transpose_f32_bf16(const float* __restrict__ W,
                                                          unsigned short* __restrict__ Wt,
                                                          int K, int N) {
  __shared__ float tile[64][65];
  int n0 = blockIdx.x * 64, k0 = blockIdx.y * 64;
  int t = threadIdx.x;
  int lr = t >> 4, lc = (t & 15) * 4;
#pragma unroll
  for (int i = 0; i < 4; ++i) {
    int k = lr + i * 16;
    float4 v = *(const float4*)&W[(size_t)(k0 + k) * N + n0 + lc];
    tile[k][lc] = v.x; tile[k][lc + 1] = v.y; tile[k][lc + 2] = v.z; tile[k][lc + 3] = v.w;
  }
  __syncthreads();
  int n = t >> 2, kc = (t & 3) * 16;
  unsigned short* dst = &Wt[(size_t)(n0 + n) * K + k0 + kc];
#pragma unroll
  for (int j = 0; j < 16; ++j) dst[j] = f2bf(tile[kc + j][n]);
}

// ---------------- RoPE tables: cos/sin [T][32] ----------------
__global__ __launch_bounds__(256) void rope_tab(float* __restrict__ cosT, float* __restrict__ sinT) {
  int i = blockIdx.x * 256 + threadIdx.x;  // < 2048*32
  int t = i >> 5, j = i & 31;
  float inv = powf(10000.0f, -(float)j * (1.0f / 32.0f));
  float a = (float)t * inv;
  cosT[i] = cosf(a);
  sinT[i] = sinf(a);
}

// ---------------- NT GEMM: C[M][N] = A[M][K] * Bt[N][K]^T  (bf16 in, fp32 acc) ----------
template <typename OutT>
__global__ __launch_bounds__(256) void gemm_nt(const unsigned short* __restrict__ A,
                                               const unsigned short* __restrict__ Bt,
                                               OutT* __restrict__ C, int M, int N, int K) {
  __shared__ unsigned short As[128 * 32];
  __shared__ unsigned short Bs[128 * 32];
  const int tid = threadIdx.x;
  const int w = tid >> 6, lane = tid & 63;
  const int l15 = lane & 15, lg = lane >> 4;
  const int wr = w >> 1, wc = w & 1;
  const int m0 = blockIdx.y * 128, n0 = blockIdx.x * 128;

  f32x4 acc[4][4] = {};
  const int nk = K >> 5;
  for (int kt = 0; kt < nk; ++kt) {
    const int k0 = kt * 32;
    __syncthreads();
#pragma unroll
    for (int i = 0; i < 2; ++i) {
      int c = w + i * 4;                       // chunk 0..7, wave-uniform
      int o = c * 1024 + lane * 16;            // byte offset in 8KB tile
      int row = o >> 6, kb = o & 63;           // 64B per row (32 bf16)
      llds16((const char*)A + ((size_t)(m0 + row) * K + k0) * 2 + kb,
             (char*)As + c * 1024);
      llds16((const char*)Bt + ((size_t)(n0 + row) * K + k0) * 2 + kb,
             (char*)Bs + c * 1024);
    }
    __syncthreads();
    bf16x8 af[4], bfr[4];
#pragma unroll
    for (int m = 0; m < 4; ++m)
      af[m] = *(const bf16x8*)&As[(wr * 64 + m * 16 + l15) * 32 + lg * 8];
#pragma unroll
    for (int n = 0; n < 4; ++n)
      bfr[n] = *(const bf16x8*)&Bs[(wc * 64 + n * 16 + l15) * 32 + lg * 8];
#pragma unroll
    for (int m = 0; m < 4; ++m)
#pragma unroll
      for (int n = 0; n < 4; ++n)
        acc[m][n] = __builtin_amdgcn_mfma_f32_16x16x32_bf16(af[m], bfr[n], acc[m][n], 0, 0, 0);
  }
#pragma unroll
  for (int m = 0; m < 4; ++m)
#pragma unroll
    for (int n = 0; n < 4; ++n) {
      int row = m0 + wr * 64 + m * 16 + lg * 4;
      int col = n0 + wc * 64 + n * 16 + l15;
#pragma unroll
      for (int r = 0; r < 4; ++r) {
        if constexpr (std::is_same<OutT, float>::value)
          C[(size_t)(row + r) * N + col] = acc[m][n][r];
        else
          C[(size_t)(row + r) * N + col] = f2bf(acc[m][n][r]);
      }
    }
}

// ---------------- per-head RMSNorm + RoPE + relayout (Q,K only) ----------------
// qkv bf16 [B*T][3C] -> Qr/Kr bf16 [B*H][T][64]
// Q pre-scaled by log2(e)/8 so attention softmax is a bare exp2.
__global__ __launch_bounds__(256) void qkv_post(const unsigned short* __restrict__ qkv,
                                                const float* __restrict__ qw,
                                                const float* __restrict__ kw,
                                                const float* __restrict__ cosT,
                                                const float* __restrict__ sinT,
                                                unsigned short* __restrict__ Qr,
                                                unsigned short* __restrict__ Kr) {
  int bt = blockIdx.x;
  int b = bt >> 11, t = bt & 2047;
  int tid = threadIdx.x, h = tid >> 4, g = tid & 15, d0 = g * 4;
  const unsigned short* base = qkv + (size_t)bt * 3072;
  int dm = d0 & 31;
  float4 cv = *(const float4*)&cosT[t * 32 + dm];
  float4 sv = *(const float4*)&sinT[t * 32 + dm];
  float sgn = (g < 8) ? -1.0f : 1.0f;
  size_t oofs = (((size_t)(b * 16 + h)) * 2048 + t) * 64 + d0;

#pragma unroll
  for (int s = 0; s < 2; ++s) {
    const float* wt = s ? kw : qw;
    float scale = s ? 1.0f : 0.18033688011112042f;   // log2(e)/8
    unsigned short* outp = s ? Kr : Qr;
    ushort4 raw = *(const ushort4*)(base + s * 1024 + h * 64 + d0);
    float x0 = bf2f(raw.x), x1 = bf2f(raw.y), x2 = bf2f(raw.z), x3 = bf2f(raw.w);
    float ssq = x0 * x0 + x1 * x1 + x2 * x2 + x3 * x3;
    ssq += __shfl_xor(ssq, 1); ssq += __shfl_xor(ssq, 2);
    ssq += __shfl_xor(ssq, 4); ssq += __shfl_xor(ssq, 8);
    float f = rsqrtf(ssq * (1.0f / 64.0f) + 1e-5f);
    float4 w4 = *(const float4*)&wt[d0];
    float n0 = x0 * f * w4.x, n1 = x1 * f * w4.y, n2 = x2 * f * w4.z, n3 = x3 * f * w4.w;
    float p0 = __shfl_xor(n0, 8), p1 = __shfl_xor(n1, 8), p2 = __shfl_xor(n2, 8), p3 = __shfl_xor(n3, 8);
    float o0 = (n0 * cv.x + sgn * p0 * sv.x) * scale;
    float o1 = (n1 * cv.y + sgn * p1 * sv.y) * scale;
    float o2 = (n2 * cv.z + sgn * p2 * sv.z) * scale;
    float o3 = (n3 * cv.w + sgn * p3 * sv.w) * scale;
    uint2 pk;
    pk.x = (unsigned)f2bf(o0) | ((unsigned)f2bf(o1) << 16);
    pk.y = (unsigned)f2bf(o2) | ((unsigned)f2bf(o3) << 16);
    *(uint2*)(outp + oofs) = pk;
  }
}

// ---------------- V transpose: qkv V-part [B*T][...] -> Vtg [B*H][64 d][2048 t] -------
__global__ __launch_bounds__(256) void vtrans(const unsigned short* __restrict__ qkv,
                                              unsigned short* __restrict__ Vtg) {
  __shared__ unsigned short tile[64][72];
  int bh = blockIdx.y, b = bh >> 4, h = bh & 15;
  int t0 = blockIdx.x * 64;
  int tid = threadIdx.x;
  int r = tid >> 2, c0 = (tid & 3) * 16;
  const unsigned short* src = qkv + (size_t)(b * 2048 + t0 + r) * 3072 + 2048 + h * 64 + c0;
  *(bf16x8*)&tile[r][c0] = *(const bf16x8*)src;
  *(bf16x8*)&tile[r][c0 + 8] = *(const bf16x8*)(src + 8);
  __syncthreads();
  int d = tid >> 2, t4 = (tid & 3) * 16;
  unsigned short* dst = &Vtg[((size_t)bh * 64 + d) * 2048 + t0 + t4];
  unsigned short pack[16];
#pragma unroll
  for (int j = 0; j < 16; ++j) pack[j] = tile[t4 + j][d];
  *(bf16x8*)dst = *(bf16x8*)&pack[0];
  *(bf16x8*)(dst + 8) = *(bf16x8*)&pack[8];
}

// ---------------- causal flash attention, fixed-max softmax, paired q-tiles ------------
// Q,K: [B*H][T][64] bf16 (Q pre-scaled by log2e/8). Vtg: [B*H][64][T] bf16.
// Y: [B][T][H*64] bf16.
// QBLK=64 (4 waves x 16 rows), KVBLK=64. Block (bh, p) processes q-tiles
// {31-p, p}: (32-p) + (p+1) = 33 kv-tile iterations for EVERY block -> uniform
// load, no tail. bh on blockIdx.x so one head's blocks share an XCD (L2 reuse).
// |q.k|/8 <= 8 (RMSNormed rows, RoPE rotation) -> fixed-max softmax: p=exp2(s),
// per-lane psum, one reduce at the end, no rescale.
__global__ __launch_bounds__(256) void attn_fwd(const unsigned short* __restrict__ Q,
                                                const unsigned short* __restrict__ K,
                                                const unsigned short* __restrict__ Vtg,
                                                unsigned short* __restrict__ Y) {
  const int bh = blockIdx.x;        // 0..63
  const int pr = blockIdx.y;        // 0..15
  const int b = bh >> 4, h = bh & 15;
  const int tid = threadIdx.x;
  const int w = tid >> 6, lane = tid & 63;
  const int l15 = lane & 15, lg = lane >> 4;

  __shared__ unsigned short Kl[2][64 * 64];   // swizzled [k][d], 128B rows
  __shared__ unsigned short Vt[2][64 * 64];   // swizzled [d][k], 128B rows
  __shared__ unsigned short Pl[4][16][68];    // per-wave P [q_local][k]

  const size_t bhT = (size_t)bh * 2048;
  const char* Kg = (const char*)(K + bhT * 64);          // row stride 128B
  const char* Vg = (const char*)(Vtg + bhT * 64);        // row stride 4096B

  auto stage = [&](int buf, int kt) {
#pragma unroll
    for (int i = 0; i < 2; ++i) {
      int c = w * 2 + i;                     // chunk 0..7, wave-uniform
      int pos = c * 1024 + lane * 16;        // linear byte in 8KB tile
      int row = pos >> 7, cb = pos & 127;
      int srcb = cb ^ ((row & 7) << 4);      // inverse-swizzled source
      llds16(Kg + ((size_t)(kt * 64 + row)) * 128 + srcb,
             (char*)&Kl[buf][0] + c * 1024);
      llds16(Vg + (size_t)row * 4096 + (size_t)kt * 128 + srcb,
             (char*)&Vt[buf][0] + c * 1024);
    }
  };

  auto run_qtile = [&](int qtb) {
    const int qbase = qtb * 64;
    const unsigned short* Qp = Q + (bhT + qbase + w * 16 + l15) * 64 + lg * 8;
    bf16x8 aq[2];
    aq[0] = *(const bf16x8*)(Qp);
    aq[1] = *(const bf16x8*)(Qp + 32);

    f32x4 o[4] = {};
    float psum[4] = {};

    for (int kt = 0; kt <= qtb; ++kt) {
      const int cur = kt & 1;
      if (kt < qtb) stage(cur ^ 1, kt + 1);
      const char* Kc = (const char*)&Kl[cur][0];
      const char* Vc = (const char*)&Vt[cur][0];

      f32x4 s[4] = {};
      __builtin_amdgcn_s_setprio(1);
#pragma unroll
      for (int n = 0; n < 4; ++n) {
        int r = n * 16 + l15, sw = (r & 7) << 4;
#pragma unroll
        for (int ks = 0; ks < 2; ++ks) {
          bf16x8 bk = *(const bf16x8*)(Kc + r * 128 + ((ks * 64 + lg * 16) ^ sw));
          s[n] = __builtin_amdgcn_mfma_f32_16x16x32_bf16(aq[ks], bk, s[n], 0, 0, 0);
        }
      }
      __builtin_amdgcn_s_setprio(0);

      if (kt == qtb) {   // diagonal tile: causal mask
#pragma unroll
        for (int n = 0; n < 4; ++n) {
          int kg = n * 16 + l15;
#pragma unroll
          for (int r = 0; r < 4; ++r) {
            int qg = w * 16 + lg * 4 + r;
            if (kg > qg) s[n][r] = -1e30f;
          }
        }
      }

      // p = exp2(s); accumulate per-lane psum; store P (round-half-up bf16)
#pragma unroll
      for (int n = 0; n < 4; ++n)
#pragma unroll
        for (int r = 0; r < 4; ++r) {
          float p = __builtin_exp2f(s[n][r]);
          psum[r] += p;
          unsigned int u = (__builtin_bit_cast(unsigned int, p) + 0x8000u) >> 16;
          Pl[w][lg * 4 + r][n * 16 + l15] = (unsigned short)u;
        }
      asm volatile("" ::: "memory");  // keep P stores before P reads (per-wave LDS in-order)

      bf16x8 ap[2];
      ap[0] = *(const bf16x8*)&Pl[w][l15][lg * 8];
      ap[1] = *(const bf16x8*)&Pl[w][l15][32 + lg * 8];

      __builtin_amdgcn_s_setprio(1);
#pragma unroll
      for (int df = 0; df < 4; ++df) {
        int rr = df * 16 + l15, sw = (rr & 7) << 4;
#pragma unroll
        for (int ks = 0; ks < 2; ++ks) {
          bf16x8 bv = *(const bf16x8*)(Vc + rr * 128 + ((ks * 64 + lg * 16) ^ sw));
          o[df] = __builtin_amdgcn_mfma_f32_16x16x32_bf16(ap[ks], bv, o[df], 0, 0, 0);
        }
      }
      __builtin_amdgcn_s_setprio(0);
      __syncthreads();  // drains next-tile staging; protects cur from overwrite
    }

#pragma unroll
    for (int r = 0; r < 4; ++r) {
      float l = psum[r];
      l += __shfl_xor(l, 1); l += __shfl_xor(l, 2);
      l += __shfl_xor(l, 4); l += __shfl_xor(l, 8);
      float inv = 1.0f / l;
      size_t q = qbase + w * 16 + lg * 4 + r;
      unsigned short* yp = Y + ((size_t)b * 2048 + q) * 1024 + h * 64;
#pragma unroll
      for (int df = 0; df < 4; ++df) yp[df * 16 + l15] = f2bf(o[df][r] * inv);
    }
  };

  // heavy segment then light segment; every block: 33 kv-tile iterations total
  stage(0, 0);
  __syncthreads();
  run_qtile(31 - pr);
  stage(0, 0);
  __syncthreads();
  run_qtile(pr);
}

// ---------------- launch ----------------
extern "C" void kernel_launch(void* const* d_in, const int* in_sizes, int n_in,
                              void* d_out, int out_size, void* d_ws, size_t ws_size,
                              hipStream_t stream) {
  const float* x = (const float*)d_in[0];
  const float* Wqkv = (const float*)d_in[1];
  const float* Wproj = (const float*)d_in[2];
  const float* qw = (const float*)d_in[3];
  const float* kw = (const float*)d_in[4];
  float* out = (float*)d_out;

  char* ws = (char*)d_ws;
  unsigned short* xb = (unsigned short*)ws;        ws += (size_t)8192 * 1024 * 2;
  unsigned short* wqkvt = (unsigned short*)ws;     ws += (size_t)3072 * 1024 * 2;
  unsigned short* wprojt = (unsigned short*)ws;    ws += (size_t)1024 * 1024 * 2;
  unsigned short* qkvb = (unsigned short*)ws;      ws += (size_t)8192 * 3072 * 2;
  unsigned short* Qr = (unsigned short*)ws;        ws += (size_t)64 * 2048 * 64 * 2;
  unsigned short* Kr = (unsigned short*)ws;        ws += (size_t)64 * 2048 * 64 * 2;
  unsigned short* Vtg = (unsigned short*)ws;       ws += (size_t)64 * 64 * 2048 * 2;
  unsigned short* yb = (unsigned short*)ws;        ws += (size_t)8192 * 1024 * 2;
  float* cosT = (float*)ws;                        ws += (size_t)2048 * 32 * 4;
  float* sinT = (float*)ws;                        ws += (size_t)2048 * 32 * 4;

  cvt_f32_bf16<<<2048, 256, 0, stream>>>(x, xb, 8192 * 1024 / 4);
  transpose_f32_bf16<<<dim3(48, 16), 256, 0, stream>>>(Wqkv, wqkvt, 1024, 3072);
  transpose_f32_bf16<<<dim3(16, 16), 256, 0, stream>>>(Wproj, wprojt, 1024, 1024);
  rope_tab<<<256, 256, 0, stream>>>(cosT, sinT);
  gemm_nt<unsigned short><<<dim3(24, 64), 256, 0, stream>>>(xb, wqkvt, qkvb, 8192, 3072, 1024);
  qkv_post<<<8192, 256, 0, stream>>>(qkvb, qw, kw, cosT, sinT, Qr, Kr);
  vtrans<<<dim3(32, 64), 256, 0, stream>>>(qkvb, Vtg);
  attn_fwd<<<dim3(64, 16), 256, 0, stream>>>(Qr, Kr, Vtg, yb);
  gemm_nt<float><<<dim3(8, 64), 256, 0, stream>>>(yb, wprojt, out, 8192, 1024, 1024);
}

// Round 5
// 238.669 us; speedup vs baseline: 1.8970x; 1.0078x over previous
//
#include <hip/hip_runtime.h>
#include <cstdint>
#include <type_traits>

// ---------------- common types / helpers ----------------
typedef __attribute__((ext_vector_type(8))) short bf16x8;   // 8 bf16 in 4 VGPRs
typedef __attribute__((ext_vector_type(4))) float f32x4;

typedef unsigned int __attribute__((address_space(1))) as1_uint;
typedef unsigned int __attribute__((address_space(3))) as3_uint;

__device__ __forceinline__ void llds16(const void* g, void* l) {
  // async global->LDS, 16B per lane; LDS dst is wave-uniform base + lane*16
  __builtin_amdgcn_global_load_lds((const as1_uint*)g, (as3_uint*)l, 16, 0, 0);
}

__device__ __forceinline__ unsigned short f2bf(float f) {
  unsigned int u = __builtin_bit_cast(unsigned int, f);
  u = (u + 0x7fffu + ((u >> 16) & 1u)) >> 16;   // RNE
  return (unsigned short)u;
}
__device__ __forceinline__ float bf2f(unsigned short h) {
  unsigned int u = ((unsigned int)h) << 16;
  return __builtin_bit_cast(float, u);
}

// ---------------- elementwise convert f32 -> bf16 ----------------
__global__ __launch_bounds__(256) void cvt_f32_bf16(const float* __restrict__ in,
                                                    unsigned short* __restrict__ out, int n4) {
  int i = blockIdx.x * blockDim.x + threadIdx.x;
  int stride = gridDim.x * blockDim.x;
  for (; i < n4; i += stride) {
    float4 v = ((const float4*)in)[i];
    uint2 p;
    p.x = (unsigned)f2bf(v.x) | ((unsigned)f2bf(v.y) << 16);
    p.y = (unsigned)f2bf(v.z) | ((unsigned)f2bf(v.w) << 16);
    ((uint2*)out)[i] = p;
  }
}

// ---------------- transpose + convert: W[K][N] f32 -> Wt[N][K] bf16 ----------------
__global__ __launch_bounds__(256) void transpose_f32_bf16(const float* __restrict__ W,
                                                          unsigned short* __restrict__ Wt,
                                                          int K, int N) {
  __shared__ float tile[64][65];
  int n0 = blockIdx.x * 64, k0 = blockIdx.y * 64;
  int t = threadIdx.x;
  int lr = t >> 4, lc = (t & 15) * 4;
#pragma unroll
  for (int i = 0; i < 4; ++i) {
    int k = lr + i * 16;
    float4 v = *(const float4*)&W[(size_t)(k0 + k) * N + n0 + lc];
    tile[k][lc] = v.x; tile[k][lc + 1] = v.y; tile[k][lc + 2] = v.z; tile[k][lc + 3] = v.w;
  }
  __syncthreads();
  int n = t >> 2, kc = (t & 3) * 16;
  unsigned short* dst = &Wt[(size_t)(n0 + n) * K + k0 + kc];
#pragma unroll
  for (int j = 0; j < 16; ++j) dst[j] = f2bf(tile[kc + j][n]);
}

// ---------------- RoPE tables: cos/sin [T][32] ----------------
__global__ __launch_bounds__(256) void rope_tab(float* __restrict__ cosT, float* __restrict__ sinT) {
  int i = blockIdx.x * 256 + threadIdx.x;  // < 2048*32
  int t = i >> 5, j = i & 31;
  float inv = powf(10000.0f, -(float)j * (1.0f / 32.0f));
  float a = (float)t * inv;
  cosT[i] = cosf(a);
  sinT[i] = sinf(a);
}

// ---------------- NT GEMM: C[M][N] = A[M][K] * Bt[N][K]^T  (bf16 in, fp32 acc) ----------
template <typename OutT>
__global__ __launch_bounds__(256) void gemm_nt(const unsigned short* __restrict__ A,
                                               const unsigned short* __restrict__ Bt,
                                               OutT* __restrict__ C, int M, int N, int K) {
  __shared__ unsigned short As[128 * 32];
  __shared__ unsigned short Bs[128 * 32];
  const int tid = threadIdx.x;
  const int w = tid >> 6, lane = tid & 63;
  const int l15 = lane & 15, lg = lane >> 4;
  const int wr = w >> 1, wc = w & 1;
  const int m0 = blockIdx.y * 128, n0 = blockIdx.x * 128;

  f32x4 acc[4][4] = {};
  const int nk = K >> 5;
  for (int kt = 0; kt < nk; ++kt) {
    const int k0 = kt * 32;
    __syncthreads();
#pragma unroll
    for (int i = 0; i < 2; ++i) {
      int c = w + i * 4;                       // chunk 0..7, wave-uniform
      int o = c * 1024 + lane * 16;            // byte offset in 8KB tile
      int row = o >> 6, kb = o & 63;           // 64B per row (32 bf16)
      llds16((const char*)A + ((size_t)(m0 + row) * K + k0) * 2 + kb,
             (char*)As + c * 1024);
      llds16((const char*)Bt + ((size_t)(n0 + row) * K + k0) * 2 + kb,
             (char*)Bs + c * 1024);
    }
    __syncthreads();
    bf16x8 af[4], bfr[4];
#pragma unroll
    for (int m = 0; m < 4; ++m)
      af[m] = *(const bf16x8*)&As[(wr * 64 + m * 16 + l15) * 32 + lg * 8];
#pragma unroll
    for (int n = 0; n < 4; ++n)
      bfr[n] = *(const bf16x8*)&Bs[(wc * 64 + n * 16 + l15) * 32 + lg * 8];
#pragma unroll
    for (int m = 0; m < 4; ++m)
#pragma unroll
      for (int n = 0; n < 4; ++n)
        acc[m][n] = __builtin_amdgcn_mfma_f32_16x16x32_bf16(af[m], bfr[n], acc[m][n], 0, 0, 0);
  }
#pragma unroll
  for (int m = 0; m < 4; ++m)
#pragma unroll
    for (int n = 0; n < 4; ++n) {
      int row = m0 + wr * 64 + m * 16 + lg * 4;
      int col = n0 + wc * 64 + n * 16 + l15;
#pragma unroll
      for (int r = 0; r < 4; ++r) {
        if constexpr (std::is_same<OutT, float>::value)
          C[(size_t)(row + r) * N + col] = acc[m][n][r];
        else
          C[(size_t)(row + r) * N + col] = f2bf(acc[m][n][r]);
      }
    }
}

// ---------------- per-head RMSNorm + RoPE + relayout (Q,K only) ----------------
// qkv bf16 [B*T][3C] -> Qr/Kr bf16 [B*H][T][64]
// Q pre-scaled by log2(e)/8 so attention softmax is a bare exp2.
__global__ __launch_bounds__(256) void qkv_post(const unsigned short* __restrict__ qkv,
                                                const float* __restrict__ qw,
                                                const float* __restrict__ kw,
                                                const float* __restrict__ cosT,
                                                const float* __restrict__ sinT,
                                                unsigned short* __restrict__ Qr,
                                                unsigned short* __restrict__ Kr) {
  int bt = blockIdx.x;
  int b = bt >> 11, t = bt & 2047;
  int tid = threadIdx.x, h = tid >> 4, g = tid & 15, d0 = g * 4;
  const unsigned short* base = qkv + (size_t)bt * 3072;
  int dm = d0 & 31;
  float4 cv = *(const float4*)&cosT[t * 32 + dm];
  float4 sv = *(const float4*)&sinT[t * 32 + dm];
  float sgn = (g < 8) ? -1.0f : 1.0f;
  size_t oofs = (((size_t)(b * 16 + h)) * 2048 + t) * 64 + d0;

#pragma unroll
  for (int s = 0; s < 2; ++s) {
    const float* wt = s ? kw : qw;
    float scale = s ? 1.0f : 0.18033688011112042f;   // log2(e)/8
    unsigned short* outp = s ? Kr : Qr;
    ushort4 raw = *(const ushort4*)(base + s * 1024 + h * 64 + d0);
    float x0 = bf2f(raw.x), x1 = bf2f(raw.y), x2 = bf2f(raw.z), x3 = bf2f(raw.w);
    float ssq = x0 * x0 + x1 * x1 + x2 * x2 + x3 * x3;
    ssq += __shfl_xor(ssq, 1); ssq += __shfl_xor(ssq, 2);
    ssq += __shfl_xor(ssq, 4); ssq += __shfl_xor(ssq, 8);
    float f = rsqrtf(ssq * (1.0f / 64.0f) + 1e-5f);
    float4 w4 = *(const float4*)&wt[d0];
    float n0 = x0 * f * w4.x, n1 = x1 * f * w4.y, n2 = x2 * f * w4.z, n3 = x3 * f * w4.w;
    float p0 = __shfl_xor(n0, 8), p1 = __shfl_xor(n1, 8), p2 = __shfl_xor(n2, 8), p3 = __shfl_xor(n3, 8);
    float o0 = (n0 * cv.x + sgn * p0 * sv.x) * scale;
    float o1 = (n1 * cv.y + sgn * p1 * sv.y) * scale;
    float o2 = (n2 * cv.z + sgn * p2 * sv.z) * scale;
    float o3 = (n3 * cv.w + sgn * p3 * sv.w) * scale;
    uint2 pk;
    pk.x = (unsigned)f2bf(o0) | ((unsigned)f2bf(o1) << 16);
    pk.y = (unsigned)f2bf(o2) | ((unsigned)f2bf(o3) << 16);
    *(uint2*)(outp + oofs) = pk;
  }
}

// ---------------- V transpose: qkv V-part [B*T][...] -> Vtg [B*H][64 d][2048 t] -------
__global__ __launch_bounds__(256) void vtrans(const unsigned short* __restrict__ qkv,
                                              unsigned short* __restrict__ Vtg) {
  __shared__ unsigned short tile[64][72];
  int bh = blockIdx.y, b = bh >> 4, h = bh & 15;
  int t0 = blockIdx.x * 64;
  int tid = threadIdx.x;
  int r = tid >> 2, c0 = (tid & 3) * 16;
  const unsigned short* src = qkv + (size_t)(b * 2048 + t0 + r) * 3072 + 2048 + h * 64 + c0;
  *(bf16x8*)&tile[r][c0] = *(const bf16x8*)src;
  *(bf16x8*)&tile[r][c0 + 8] = *(const bf16x8*)(src + 8);
  __syncthreads();
  int d = tid >> 2, t4 = (tid & 3) * 16;
  unsigned short* dst = &Vtg[((size_t)bh * 64 + d) * 2048 + t0 + t4];
  unsigned short pack[16];
#pragma unroll
  for (int j = 0; j < 16; ++j) pack[j] = tile[t4 + j][d];
  *(bf16x8*)dst = *(bf16x8*)&pack[0];
  *(bf16x8*)(dst + 8) = *(bf16x8*)&pack[8];
}

// ---------------- causal flash attention, fixed-max softmax, paired q-tiles ------------
// Q,K: [B*H][T][64] bf16 (Q pre-scaled by log2e/8). Vtg: [B*H][64][T] bf16.
// Y: [B][T][H*64] bf16.
// QBLK=64 (4 waves x 16 rows), KVBLK=64. Block (bh, p) processes q-tiles
// {31-p, p} -> 33 kv-tile iterations for EVERY block (uniform load, no tail).
// LDS exactly 40960 B = 160KiB/4 -> 4 blocks/CU co-resident in ONE pass.
// P buffer: 64-stride, XOR-swizzled (col ^ ((row&7)<<3)) -> conflict-clean.
// |q.k|/8 <= 8 (RMSNormed rows, RoPE rotation) -> fixed-max softmax: p=exp2(s),
// per-lane psum, one reduce at the end, no rescale.
__global__ __launch_bounds__(256) void attn_fwd(const unsigned short* __restrict__ Q,
                                                const unsigned short* __restrict__ K,
                                                const unsigned short* __restrict__ Vtg,
                                                unsigned short* __restrict__ Y) {
  const int bh = blockIdx.x;        // 0..63
  const int pr = blockIdx.y;        // 0..15
  const int b = bh >> 4, h = bh & 15;
  const int tid = threadIdx.x;
  const int w = tid >> 6, lane = tid & 63;
  const int l15 = lane & 15, lg = lane >> 4;

  __shared__ unsigned short Kl[2][64 * 64];   // swizzled [k][d], 128B rows (16384 B)
  __shared__ unsigned short Vt[2][64 * 64];   // swizzled [d][k], 128B rows (16384 B)
  __shared__ unsigned short Pl[4][16 * 64];   // per-wave P, 64-stride XOR-swz (8192 B)

  const size_t bhT = (size_t)bh * 2048;
  const char* Kg = (const char*)(K + bhT * 64);          // row stride 128B
  const char* Vg = (const char*)(Vtg + bhT * 64);        // row stride 4096B

  auto stage = [&](int buf, int kt) {
#pragma unroll
    for (int i = 0; i < 2; ++i) {
      int c = w * 2 + i;                     // chunk 0..7, wave-uniform
      int pos = c * 1024 + lane * 16;        // linear byte in 8KB tile
      int row = pos >> 7, cb = pos & 127;
      int srcb = cb ^ ((row & 7) << 4);      // inverse-swizzled source
      llds16(Kg + ((size_t)(kt * 64 + row)) * 128 + srcb,
             (char*)&Kl[buf][0] + c * 1024);
      llds16(Vg + (size_t)row * 4096 + (size_t)kt * 128 + srcb,
             (char*)&Vt[buf][0] + c * 1024);
    }
  };

  auto run_qtile = [&](int qtb) {
    const int qbase = qtb * 64;
    const unsigned short* Qp = Q + (bhT + qbase + w * 16 + l15) * 64 + lg * 8;
    bf16x8 aq[2];
    aq[0] = *(const bf16x8*)(Qp);
    aq[1] = *(const bf16x8*)(Qp + 32);

    f32x4 o[4] = {};
    float psum[4] = {};

    for (int kt = 0; kt <= qtb; ++kt) {
      const int cur = kt & 1;
      if (kt < qtb) stage(cur ^ 1, kt + 1);
      const char* Kc = (const char*)&Kl[cur][0];
      const char* Vc = (const char*)&Vt[cur][0];

      f32x4 s[4] = {};
      __builtin_amdgcn_s_setprio(1);
#pragma unroll
      for (int n = 0; n < 4; ++n) {
        int r = n * 16 + l15, sw = (r & 7) << 4;
#pragma unroll
        for (int ks = 0; ks < 2; ++ks) {
          bf16x8 bk = *(const bf16x8*)(Kc + r * 128 + ((ks * 64 + lg * 16) ^ sw));
          s[n] = __builtin_amdgcn_mfma_f32_16x16x32_bf16(aq[ks], bk, s[n], 0, 0, 0);
        }
      }
      __builtin_amdgcn_s_setprio(0);

      if (kt == qtb) {   // diagonal tile: causal mask
#pragma unroll
        for (int n = 0; n < 4; ++n) {
          int kg = n * 16 + l15;
#pragma unroll
          for (int r = 0; r < 4; ++r) {
            int qg = w * 16 + lg * 4 + r;
            if (kg > qg) s[n][r] = -1e30f;
          }
        }
      }

      // p = exp2(s); accumulate per-lane psum; store P swizzled (round-half-up bf16)
#pragma unroll
      for (int n = 0; n < 4; ++n)
#pragma unroll
        for (int r = 0; r < 4; ++r) {
          float p = __builtin_exp2f(s[n][r]);
          psum[r] += p;
          unsigned int u = (__builtin_bit_cast(unsigned int, p) + 0x8000u) >> 16;
          int prow = lg * 4 + r;
          Pl[w][prow * 64 + ((n * 16 + l15) ^ ((prow & 7) << 3))] = (unsigned short)u;
        }
      asm volatile("" ::: "memory");  // keep P stores before P reads (per-wave LDS in-order)

      bf16x8 ap[2];
      ap[0] = *(const bf16x8*)&Pl[w][l15 * 64 + ((lg * 8) ^ ((l15 & 7) << 3))];
      ap[1] = *(const bf16x8*)&Pl[w][l15 * 64 + ((32 + lg * 8) ^ ((l15 & 7) << 3))];

      __builtin_amdgcn_s_setprio(1);
#pragma unroll
      for (int df = 0; df < 4; ++df) {
        int rr = df * 16 + l15, sw = (rr & 7) << 4;
#pragma unroll
        for (int ks = 0; ks < 2; ++ks) {
          bf16x8 bv = *(const bf16x8*)(Vc + rr * 128 + ((ks * 64 + lg * 16) ^ sw));
          o[df] = __builtin_amdgcn_mfma_f32_16x16x32_bf16(ap[ks], bv, o[df], 0, 0, 0);
        }
      }
      __builtin_amdgcn_s_setprio(0);
      __syncthreads();  // drains next-tile staging; protects cur from overwrite
    }

#pragma unroll
    for (int r = 0; r < 4; ++r) {
      float l = psum[r];
      l += __shfl_xor(l, 1); l += __shfl_xor(l, 2);
      l += __shfl_xor(l, 4); l += __shfl_xor(l, 8);
      float inv = 1.0f / l;
      size_t q = qbase + w * 16 + lg * 4 + r;
      unsigned short* yp = Y + ((size_t)b * 2048 + q) * 1024 + h * 64;
#pragma unroll
      for (int df = 0; df < 4; ++df) yp[df * 16 + l15] = f2bf(o[df][r] * inv);
    }
  };

  // heavy segment then light segment; every block: 33 kv-tile iterations total
  stage(0, 0);
  __syncthreads();
  run_qtile(31 - pr);
  stage(0, 0);
  __syncthreads();
  run_qtile(pr);
}

// ---------------- launch ----------------
extern "C" void kernel_launch(void* const* d_in, const int* in_sizes, int n_in,
                              void* d_out, int out_size, void* d_ws, size_t ws_size,
                              hipStream_t stream) {
  const float* x = (const float*)d_in[0];
  const float* Wqkv = (const float*)d_in[1];
  const float* Wproj = (const float*)d_in[2];
  const float* qw = (const float*)d_in[3];
  const float* kw = (const float*)d_in[4];
  float* out = (float*)d_out;

  char* ws = (char*)d_ws;
  unsigned short* xb = (unsigned short*)ws;        ws += (size_t)8192 * 1024 * 2;
  unsigned short* wqkvt = (unsigned short*)ws;     ws += (size_t)3072 * 1024 * 2;
  unsigned short* wprojt = (unsigned short*)ws;    ws += (size_t)1024 * 1024 * 2;
  unsigned short* qkvb = (unsigned short*)ws;      ws += (size_t)8192 * 3072 * 2;
  unsigned short* Qr = (unsigned short*)ws;        ws += (size_t)64 * 2048 * 64 * 2;
  unsigned short* Kr = (unsigned short*)ws;        ws += (size_t)64 * 2048 * 64 * 2;
  unsigned short* Vtg = (unsigned short*)ws;       ws += (size_t)64 * 64 * 2048 * 2;
  unsigned short* yb = (unsigned short*)ws;        ws += (size_t)8192 * 1024 * 2;
  float* cosT = (float*)ws;                        ws += (size_t)2048 * 32 * 4;
  float* sinT = (float*)ws;                        ws += (size_t)2048 * 32 * 4;

  cvt_f32_bf16<<<2048, 256, 0, stream>>>(x, xb, 8192 * 1024 / 4);
  transpose_f32_bf16<<<dim3(48, 16), 256, 0, stream>>>(Wqkv, wqkvt, 1024, 3072);
  transpose_f32_bf16<<<dim3(16, 16), 256, 0, stream>>>(Wproj, wprojt, 1024, 1024);
  rope_tab<<<256, 256, 0, stream>>>(cosT, sinT);
  gemm_nt<unsigned short><<<dim3(24, 64), 256, 0, stream>>>(xb, wqkvt, qkvb, 8192, 3072, 1024);
  qkv_post<<<8192, 256, 0, stream>>>(qkvb, qw, kw, cosT, sinT, Qr, Kr);
  vtrans<<<dim3(32, 64), 256, 0, stream>>>(qkvb, Vtg);
  attn_fwd<<<dim3(64, 16), 256, 0, stream>>>(Qr, Kr, Vtg, yb);
  gemm_nt<float><<<dim3(8, 64), 256, 0, stream>>>(yb, wprojt, out, 8192, 1024, 1024);
}

// Round 6
// 224.711 us; speedup vs baseline: 2.0149x; 1.0621x over previous
//
#include <hip/hip_runtime.h>
#include <cstdint>
#include <type_traits>

// ---------------- common types / helpers ----------------
typedef __attribute__((ext_vector_type(8))) short bf16x8;   // 8 bf16 in 4 VGPRs
typedef __attribute__((ext_vector_type(4))) float f32x4;

typedef unsigned int __attribute__((address_space(1))) as1_uint;
typedef unsigned int __attribute__((address_space(3))) as3_uint;

__device__ __forceinline__ void llds16(const void* g, void* l) {
  // async global->LDS, 16B per lane; LDS dst is wave-uniform base + lane*16
  __builtin_amdgcn_global_load_lds((const as1_uint*)g, (as3_uint*)l, 16, 0, 0);
}

__device__ __forceinline__ unsigned short f2bf(float f) {
  unsigned int u = __builtin_bit_cast(unsigned int, f);
  u = (u + 0x7fffu + ((u >> 16) & 1u)) >> 16;   // RNE
  return (unsigned short)u;
}
__device__ __forceinline__ float bf2f(unsigned short h) {
  unsigned int u = ((unsigned int)h) << 16;
  return __builtin_bit_cast(float, u);
}

// ---------------- elementwise convert f32 -> bf16 ----------------
__global__ __launch_bounds__(256) void cvt_f32_bf16(const float* __restrict__ in,
                                                    unsigned short* __restrict__ out, int n4) {
  int i = blockIdx.x * blockDim.x + threadIdx.x;
  int stride = gridDim.x * blockDim.x;
  for (; i < n4; i += stride) {
    float4 v = ((const float4*)in)[i];
    uint2 p;
    p.x = (unsigned)f2bf(v.x) | ((unsigned)f2bf(v.y) << 16);
    p.y = (unsigned)f2bf(v.z) | ((unsigned)f2bf(v.w) << 16);
    ((uint2*)out)[i] = p;
  }
}

// ---------------- transpose + convert: W[K][N] f32 -> Wt[N][K] bf16 ----------------
__global__ __launch_bounds__(256) void transpose_f32_bf16(const float* __restrict__ W,
                                                          unsigned short* __restrict__ Wt,
                                                          int K, int N) {
  __shared__ float tile[64][65];
  int n0 = blockIdx.x * 64, k0 = blockIdx.y * 64;
  int t = threadIdx.x;
  int lr = t >> 4, lc = (t & 15) * 4;
#pragma unroll
  for (int i = 0; i < 4; ++i) {
    int k = lr + i * 16;
    float4 v = *(const float4*)&W[(size_t)(k0 + k) * N + n0 + lc];
    tile[k][lc] = v.x; tile[k][lc + 1] = v.y; tile[k][lc + 2] = v.z; tile[k][lc + 3] = v.w;
  }
  __syncthreads();
  int n = t >> 2, kc = (t & 3) * 16;
  unsigned short* dst = &Wt[(size_t)(n0 + n) * K + k0 + kc];
#pragma unroll
  for (int j = 0; j < 16; ++j) dst[j] = f2bf(tile[kc + j][n]);
}

// ---------------- RoPE tables: cos/sin [T][32] ----------------
__global__ __launch_bounds__(256) void rope_tab(float* __restrict__ cosT, float* __restrict__ sinT) {
  int i = blockIdx.x * 256 + threadIdx.x;  // < 2048*32
  int t = i >> 5, j = i & 31;
  float inv = powf(10000.0f, -(float)j * (1.0f / 32.0f));
  float a = (float)t * inv;
  cosT[i] = cosf(a);
  sinT[i] = sinf(a);
}

// ---------------- NT GEMM: C[M][N] = A[M][K] * Bt[N][K]^T  (bf16 in, fp32 acc) ----------
template <typename OutT>
__global__ __launch_bounds__(256) void gemm_nt(const unsigned short* __restrict__ A,
                                               const unsigned short* __restrict__ Bt,
                                               OutT* __restrict__ C, int M, int N, int K) {
  __shared__ unsigned short As[128 * 32];
  __shared__ unsigned short Bs[128 * 32];
  const int tid = threadIdx.x;
  const int w = tid >> 6, lane = tid & 63;
  const int l15 = lane & 15, lg = lane >> 4;
  const int wr = w >> 1, wc = w & 1;
  const int m0 = blockIdx.y * 128, n0 = blockIdx.x * 128;

  f32x4 acc[4][4] = {};
  const int nk = K >> 5;
  for (int kt = 0; kt < nk; ++kt) {
    const int k0 = kt * 32;
    __syncthreads();
#pragma unroll
    for (int i = 0; i < 2; ++i) {
      int c = w + i * 4;                       // chunk 0..7, wave-uniform
      int o = c * 1024 + lane * 16;            // byte offset in 8KB tile
      int row = o >> 6, kb = o & 63;           // 64B per row (32 bf16)
      llds16((const char*)A + ((size_t)(m0 + row) * K + k0) * 2 + kb,
             (char*)As + c * 1024);
      llds16((const char*)Bt + ((size_t)(n0 + row) * K + k0) * 2 + kb,
             (char*)Bs + c * 1024);
    }
    __syncthreads();
    bf16x8 af[4], bfr[4];
#pragma unroll
    for (int m = 0; m < 4; ++m)
      af[m] = *(const bf16x8*)&As[(wr * 64 + m * 16 + l15) * 32 + lg * 8];
#pragma unroll
    for (int n = 0; n < 4; ++n)
      bfr[n] = *(const bf16x8*)&Bs[(wc * 64 + n * 16 + l15) * 32 + lg * 8];
#pragma unroll
    for (int m = 0; m < 4; ++m)
#pragma unroll
      for (int n = 0; n < 4; ++n)
        acc[m][n] = __builtin_amdgcn_mfma_f32_16x16x32_bf16(af[m], bfr[n], acc[m][n], 0, 0, 0);
  }
#pragma unroll
  for (int m = 0; m < 4; ++m)
#pragma unroll
    for (int n = 0; n < 4; ++n) {
      int row = m0 + wr * 64 + m * 16 + lg * 4;
      int col = n0 + wc * 64 + n * 16 + l15;
#pragma unroll
      for (int r = 0; r < 4; ++r) {
        if constexpr (std::is_same<OutT, float>::value)
          C[(size_t)(row + r) * N + col] = acc[m][n][r];
        else
          C[(size_t)(row + r) * N + col] = f2bf(acc[m][n][r]);
      }
    }
}

// ---------------- per-head RMSNorm + RoPE + relayout (Q,K only) ----------------
// qkv bf16 [B*T][3C] -> Qr/Kr bf16 [B*H][T][64]
// Q pre-scaled by log2(e)/8 so attention softmax is a bare exp2.
__global__ __launch_bounds__(256) void qkv_post(const unsigned short* __restrict__ qkv,
                                                const float* __restrict__ qw,
                                                const float* __restrict__ kw,
                                                const float* __restrict__ cosT,
                                                const float* __restrict__ sinT,
                                                unsigned short* __restrict__ Qr,
                                                unsigned short* __restrict__ Kr) {
  int bt = blockIdx.x;
  int b = bt >> 11, t = bt & 2047;
  int tid = threadIdx.x, h = tid >> 4, g = tid & 15, d0 = g * 4;
  const unsigned short* base = qkv + (size_t)bt * 3072;
  int dm = d0 & 31;
  float4 cv = *(const float4*)&cosT[t * 32 + dm];
  float4 sv = *(const float4*)&sinT[t * 32 + dm];
  float sgn = (g < 8) ? -1.0f : 1.0f;
  size_t oofs = (((size_t)(b * 16 + h)) * 2048 + t) * 64 + d0;

#pragma unroll
  for (int s = 0; s < 2; ++s) {
    const float* wt = s ? kw : qw;
    float scale = s ? 1.0f : 0.18033688011112042f;   // log2(e)/8
    unsigned short* outp = s ? Kr : Qr;
    ushort4 raw = *(const ushort4*)(base + s * 1024 + h * 64 + d0);
    float x0 = bf2f(raw.x), x1 = bf2f(raw.y), x2 = bf2f(raw.z), x3 = bf2f(raw.w);
    float ssq = x0 * x0 + x1 * x1 + x2 * x2 + x3 * x3;
    ssq += __shfl_xor(ssq, 1); ssq += __shfl_xor(ssq, 2);
    ssq += __shfl_xor(ssq, 4); ssq += __shfl_xor(ssq, 8);
    float f = rsqrtf(ssq * (1.0f / 64.0f) + 1e-5f);
    float4 w4 = *(const float4*)&wt[d0];
    float n0 = x0 * f * w4.x, n1 = x1 * f * w4.y, n2 = x2 * f * w4.z, n3 = x3 * f * w4.w;
    float p0 = __shfl_xor(n0, 8), p1 = __shfl_xor(n1, 8), p2 = __shfl_xor(n2, 8), p3 = __shfl_xor(n3, 8);
    float o0 = (n0 * cv.x + sgn * p0 * sv.x) * scale;
    float o1 = (n1 * cv.y + sgn * p1 * sv.y) * scale;
    float o2 = (n2 * cv.z + sgn * p2 * sv.z) * scale;
    float o3 = (n3 * cv.w + sgn * p3 * sv.w) * scale;
    uint2 pk;
    pk.x = (unsigned)f2bf(o0) | ((unsigned)f2bf(o1) << 16);
    pk.y = (unsigned)f2bf(o2) | ((unsigned)f2bf(o3) << 16);
    *(uint2*)(outp + oofs) = pk;
  }
}

// ---------------- V transpose: qkv V-part [B*T][...] -> Vtg [B*H][64 d][2048 t] -------
__global__ __launch_bounds__(256) void vtrans(const unsigned short* __restrict__ qkv,
                                              unsigned short* __restrict__ Vtg) {
  __shared__ unsigned short tile[64][72];
  int bh = blockIdx.y, b = bh >> 4, h = bh & 15;
  int t0 = blockIdx.x * 64;
  int tid = threadIdx.x;
  int r = tid >> 2, c0 = (tid & 3) * 16;
  const unsigned short* src = qkv + (size_t)(b * 2048 + t0 + r) * 3072 + 2048 + h * 64 + c0;
  *(bf16x8*)&tile[r][c0] = *(const bf16x8*)src;
  *(bf16x8*)&tile[r][c0 + 8] = *(const bf16x8*)(src + 8);
  __syncthreads();
  int d = tid >> 2, t4 = (tid & 3) * 16;
  unsigned short* dst = &Vtg[((size_t)bh * 64 + d) * 2048 + t0 + t4];
  unsigned short pack[16];
#pragma unroll
  for (int j = 0; j < 16; ++j) pack[j] = tile[t4 + j][d];
  *(bf16x8*)dst = *(bf16x8*)&pack[0];
  *(bf16x8*)(dst + 8) = *(bf16x8*)&pack[8];
}

// ---------------- causal flash attention: swapped operands, fixed-max softmax ----------
// Q,K: [B*H][T][64] bf16 (Q pre-scaled by log2e/8). Vtg: [B*H][64][T] bf16.
// Y: [B][T][H*64] bf16.
// Swapped-operand trick: mfma(Kfrag, Qfrag) -> S^T (lane&15 = q, rows = k), and
// mfma(Vtfrag, Pfrag) -> O^T (lane&15 = q, rows = d) with IDENTICAL LDS reads.
// Each lane owns one q column: psum is a per-lane scalar (no shuffles in loop),
// P-store is 4x ds_write_b64 (k-contiguous), Y-write is 4x ushort4.
// QBLK=64 (4 waves x 16 q), KVBLK=64, paired q-tiles {31-p, p} -> uniform load.
// |q.k|/8 <= 8 (RMSNormed rows, RoPE rotation) -> fixed-max softmax p=exp2(s).
__global__ __launch_bounds__(256) void attn_fwd(const unsigned short* __restrict__ Q,
                                                const unsigned short* __restrict__ K,
                                                const unsigned short* __restrict__ Vtg,
                                                unsigned short* __restrict__ Y) {
  const int bh = blockIdx.x;        // 0..63
  const int pr = blockIdx.y;        // 0..15
  const int b = bh >> 4, h = bh & 15;
  const int tid = threadIdx.x;
  const int w = tid >> 6, lane = tid & 63;
  const int l15 = lane & 15, lg = lane >> 4;

  __shared__ unsigned short Kl[2][64 * 64];   // swizzled [k][d], 128B rows (16384 B)
  __shared__ unsigned short Vt[2][64 * 64];   // swizzled [d][k], 128B rows (16384 B)
  __shared__ unsigned short Pl[4][16 * 64];   // per-wave P^T [q][k], 128B rows, swz (8192 B)

  const size_t bhT = (size_t)bh * 2048;
  const char* Kg = (const char*)(K + bhT * 64);          // row stride 128B
  const char* Vg = (const char*)(Vtg + bhT * 64);        // row stride 4096B

  auto stage = [&](int buf, int kt) {
#pragma unroll
    for (int i = 0; i < 2; ++i) {
      int c = w * 2 + i;                     // chunk 0..7, wave-uniform
      int pos = c * 1024 + lane * 16;        // linear byte in 8KB tile
      int row = pos >> 7, cb = pos & 127;
      int srcb = cb ^ ((row & 7) << 4);      // inverse-swizzled source
      llds16(Kg + ((size_t)(kt * 64 + row)) * 128 + srcb,
             (char*)&Kl[buf][0] + c * 1024);
      llds16(Vg + (size_t)row * 4096 + (size_t)kt * 128 + srcb,
             (char*)&Vt[buf][0] + c * 1024);
    }
  };

  auto run_qtile = [&](int qtb) {
    const int qbase = qtb * 64;
    const unsigned short* Qp = Q + (bhT + qbase + w * 16 + l15) * 64 + lg * 8;
    bf16x8 aq[2];
    aq[0] = *(const bf16x8*)(Qp);
    aq[1] = *(const bf16x8*)(Qp + 32);

    f32x4 o[4] = {};        // O^T: lane q=l15, rows d = df*16 + lg*4 + r
    float psum = 0.0f;      // per-lane (q = l15) partial sum over its k slice

    char* Pw = (char*)&Pl[w][0];
    const int psw = (l15 & 7) << 4;       // 16B-granular XOR swizzle keyed by q-row

    for (int kt = 0; kt <= qtb; ++kt) {
      const int cur = kt & 1;
      if (kt < qtb) stage(cur ^ 1, kt + 1);
      const char* Kc = (const char*)&Kl[cur][0];
      const char* Vc = (const char*)&Vt[cur][0];

      f32x4 s[4] = {};      // S^T: lane q=l15, rows k = n*16 + lg*4 + r
      __builtin_amdgcn_s_setprio(1);
#pragma unroll
      for (int n = 0; n < 4; ++n) {
        int r = n * 16 + l15, sw = (r & 7) << 4;
#pragma unroll
        for (int ks = 0; ks < 2; ++ks) {
          bf16x8 bk = *(const bf16x8*)(Kc + r * 128 + ((ks * 64 + lg * 16) ^ sw));
          s[n] = __builtin_amdgcn_mfma_f32_16x16x32_bf16(bk, aq[ks], s[n], 0, 0, 0);
        }
      }
      __builtin_amdgcn_s_setprio(0);

      if (kt == qtb) {   // diagonal tile: causal mask (k_local > q_local)
#pragma unroll
        for (int n = 0; n < 4; ++n)
#pragma unroll
          for (int r = 0; r < 4; ++r)
            if (n * 16 + lg * 4 + r > w * 16 + l15) s[n][r] = -1e30f;
      }

      // p = exp2(s); per-lane psum; pack 4 k-contiguous bf16 -> one b64 LDS write
#pragma unroll
      for (int n = 0; n < 4; ++n) {
        float p0 = __builtin_exp2f(s[n][0]);
        float p1 = __builtin_exp2f(s[n][1]);
        float p2 = __builtin_exp2f(s[n][2]);
        float p3 = __builtin_exp2f(s[n][3]);
        psum += (p0 + p1) + (p2 + p3);
        uint2 pk;
        pk.x = ((__builtin_bit_cast(unsigned int, p0) + 0x8000u) >> 16) |
               (((__builtin_bit_cast(unsigned int, p1) + 0x8000u) >> 16) << 16);
        pk.y = ((__builtin_bit_cast(unsigned int, p2) + 0x8000u) >> 16) |
               (((__builtin_bit_cast(unsigned int, p3) + 0x8000u) >> 16) << 16);
        *(uint2*)(Pw + l15 * 128 + ((n * 32 + lg * 8) ^ psw)) = pk;
      }
      asm volatile("" ::: "memory");  // keep P stores before P reads (per-wave LDS in-order)

      bf16x8 ap[2];
      ap[0] = *(const bf16x8*)(Pw + l15 * 128 + ((lg * 16) ^ psw));
      ap[1] = *(const bf16x8*)(Pw + l15 * 128 + ((64 + lg * 16) ^ psw));

      __builtin_amdgcn_s_setprio(1);
#pragma unroll
      for (int df = 0; df < 4; ++df) {
        int rr = df * 16 + l15, sw = (rr & 7) << 4;
#pragma unroll
        for (int ks = 0; ks < 2; ++ks) {
          bf16x8 bv = *(const bf16x8*)(Vc + rr * 128 + ((ks * 64 + lg * 16) ^ sw));
          o[df] = __builtin_amdgcn_mfma_f32_16x16x32_bf16(bv, ap[ks], o[df], 0, 0, 0);
        }
      }
      __builtin_amdgcn_s_setprio(0);
      __syncthreads();  // drains next-tile staging; protects cur from overwrite
    }

    // full row-sum: combine the 4 lanes sharing this q (lg differs in bits 4..5)
    psum += __shfl_xor(psum, 16);
    psum += __shfl_xor(psum, 32);
    float inv = 1.0f / psum;

    size_t q = qbase + w * 16 + l15;
    unsigned short* yp = Y + ((size_t)b * 2048 + q) * 1024 + h * 64 + lg * 4;
#pragma unroll
    for (int df = 0; df < 4; ++df) {
      ushort4 v;
      v.x = f2bf(o[df][0] * inv);
      v.y = f2bf(o[df][1] * inv);
      v.z = f2bf(o[df][2] * inv);
      v.w = f2bf(o[df][3] * inv);
      *(ushort4*)(yp + df * 16) = v;
    }
  };

  // heavy segment then light segment; every block: 33 kv-tile iterations total
  stage(0, 0);
  __syncthreads();
  run_qtile(31 - pr);
  stage(0, 0);
  __syncthreads();
  run_qtile(pr);
}

// ---------------- launch ----------------
extern "C" void kernel_launch(void* const* d_in, const int* in_sizes, int n_in,
                              void* d_out, int out_size, void* d_ws, size_t ws_size,
                              hipStream_t stream) {
  const float* x = (const float*)d_in[0];
  const float* Wqkv = (const float*)d_in[1];
  const float* Wproj = (const float*)d_in[2];
  const float* qw = (const float*)d_in[3];
  const float* kw = (const float*)d_in[4];
  float* out = (float*)d_out;

  char* ws = (char*)d_ws;
  unsigned short* xb = (unsigned short*)ws;        ws += (size_t)8192 * 1024 * 2;
  unsigned short* wqkvt = (unsigned short*)ws;     ws += (size_t)3072 * 1024 * 2;
  unsigned short* wprojt = (unsigned short*)ws;    ws += (size_t)1024 * 1024 * 2;
  unsigned short* qkvb = (unsigned short*)ws;      ws += (size_t)8192 * 3072 * 2;
  unsigned short* Qr = (unsigned short*)ws;        ws += (size_t)64 * 2048 * 64 * 2;
  unsigned short* Kr = (unsigned short*)ws;        ws += (size_t)64 * 2048 * 64 * 2;
  unsigned short* Vtg = (unsigned short*)ws;       ws += (size_t)64 * 64 * 2048 * 2;
  unsigned short* yb = (unsigned short*)ws;        ws += (size_t)8192 * 1024 * 2;
  float* cosT = (float*)ws;                        ws += (size_t)2048 * 32 * 4;
  float* sinT = (float*)ws;                        ws += (size_t)2048 * 32 * 4;

  cvt_f32_bf16<<<2048, 256, 0, stream>>>(x, xb, 8192 * 1024 / 4);
  transpose_f32_bf16<<<dim3(48, 16), 256, 0, stream>>>(Wqkv, wqkvt, 1024, 3072);
  transpose_f32_bf16<<<dim3(16, 16), 256, 0, stream>>>(Wproj, wprojt, 1024, 1024);
  rope_tab<<<256, 256, 0, stream>>>(cosT, sinT);
  gemm_nt<unsigned short><<<dim3(24, 64), 256, 0, stream>>>(xb, wqkvt, qkvb, 8192, 3072, 1024);
  qkv_post<<<8192, 256, 0, stream>>>(qkvb, qw, kw, cosT, sinT, Qr, Kr);
  vtrans<<<dim3(32, 64), 256, 0, stream>>>(qkvb, Vtg);
  attn_fwd<<<dim3(64, 16), 256, 0, stream>>>(Qr, Kr, Vtg, yb);
  gemm_nt<float><<<dim3(8, 64), 256, 0, stream>>>(yb, wprojt, out, 8192, 1024, 1024);
}